// Round 9
// baseline (349.795 us; speedup 1.0000x reference)
//
#include <hip/hip_runtime.h>
#include <hip/hip_bf16.h>

#define EMB   1024
#define NHEAD 16
#define HDIM  64
#define BSZ   4
#define SEQ   2048
#define MROWS (BSZ*SEQ)     // 8192
#define NQKV  (3*EMB)       // 3072

typedef __bf16 bf16;
typedef __bf16 bf16v4 __attribute__((ext_vector_type(4)));
typedef __bf16 bf16v8 __attribute__((ext_vector_type(8)));
typedef float  f32v4  __attribute__((ext_vector_type(4)));
typedef int    i32v4  __attribute__((ext_vector_type(4)));

#define MFMA16(a,b,c)  __builtin_amdgcn_mfma_f32_16x16x32_bf16((a),(b),(c),0,0,0)
#define MFMAI8(a,b,c)  __builtin_amdgcn_mfma_i32_16x16x64_i8((a),(b),(c),0,0,0)

__device__ __forceinline__ void gload_lds16(const void* g, void* l) {
  __builtin_amdgcn_global_load_lds((const __attribute__((address_space(1))) void*)g,
                                   (__attribute__((address_space(3))) void*)l,
                                   16, 0, 0);
}

// VALU (DPP) max-reduce over the 16-lane row: removes ds_swizzle from the DS pipe.
#define DPP_FMAX(x, ctrl) do {                                                     \
    int _t = __builtin_amdgcn_update_dpp(0, __float_as_int(x), (ctrl), 0xf, 0xf, true); \
    (x) = fmaxf((x), __int_as_float(_t)); } while (0)

// ---------------- scale reduction + ternarize + quantize ----------------

__global__ void zero2_kernel(float* p) { p[threadIdx.x] = 0.f; }

__global__ void abs_sum_kernel(const float* __restrict__ w, int n, float* out) {
  float s = 0.f;
  for (int i = blockIdx.x * blockDim.x + threadIdx.x; i < n; i += gridDim.x * blockDim.x)
    s += fabsf(w[i]);
  #pragma unroll
  for (int off = 32; off; off >>= 1) s += __shfl_down(s, off, 64);
  __shared__ float red[4];
  int lane = threadIdx.x & 63, wid = threadIdx.x >> 6;
  if (lane == 0) red[wid] = s;
  __syncthreads();
  if (threadIdx.x == 0) atomicAdd(out, red[0] + red[1] + red[2] + red[3]);
}

// ternary weights as i8 (exact)
__global__ void ternarize_i8_kernel(const float* __restrict__ w, int n,
                                    const float* __restrict__ sum, char* __restrict__ out) {
  int i = blockIdx.x * blockDim.x + threadIdx.x;
  if (i >= n) return;
  float scale = fmaxf(*sum / (float)n, 1e-8f);
  float t = rintf(w[i] / scale);          // RNE == jnp.round
  t = fmaxf(-1.f, fminf(1.f, t));
  out[i] = (char)(int)t;
}

// ternary weights as bf16 (for the bf16 out-projection GEMM)
__global__ void ternarize_bf16_kernel(const float* __restrict__ w, int n,
                                      const float* __restrict__ sum, bf16* __restrict__ out) {
  int i = blockIdx.x * blockDim.x + threadIdx.x;
  if (i >= n) return;
  float scale = fmaxf(*sum / (float)n, 1e-8f);
  float t = rintf(w[i] / scale);
  t = fmaxf(-1.f, fminf(1.f, t));
  out[i] = (bf16)t;
}

// x -> two i8 planes: x ~= p1/16 + p2/4096 (|err| <= 2.4e-4; exact i32 MFMA accum)
__global__ void quant_x_kernel(const float* __restrict__ x, char* __restrict__ p1,
                               char* __restrict__ p2, int n) {
  int i = blockIdx.x * blockDim.x + threadIdx.x;
  if (i >= n) return;
  float v = x[i];
  float q1 = fminf(fmaxf(rintf(v * 16.f), -127.f), 127.f);
  float r = v - q1 * 0.0625f;
  float q2 = fminf(fmaxf(rintf(r * 4096.f), -127.f), 127.f);
  p1[i] = (char)(int)q1;
  p2[i] = (char)(int)q2;
}

// ---------------- fused QKV GEMM, dual-plane i8 ----------------
// NEW: double-buffered LDS with prefetch-before-compute (attn's proven
// pattern). Old loop exposed full L2/HBM latency per kt via the barrier's
// vmcnt(0) drain between load-issue and compute. Now tile kt+1 is staged
// while tile kt computes; the next iteration's barrier drains a load that
// has had a full compute phase to land. LDS 24->48 KB (96 KB/CU at 2 blocks).
// V-transpose fused into the epilogue (R8-verified).

__launch_bounds__(256, 2)
__global__ void gemm_qkv_kernel(const char* __restrict__ xq1, const char* __restrict__ xq2,
                                const char* __restrict__ w8,
                                bf16* __restrict__ qh, bf16* __restrict__ ql,
                                bf16* __restrict__ kh, bf16* __restrict__ kl,
                                bf16* __restrict__ vt) {
  __shared__ __align__(16) char A1[2][128 * 64];
  __shared__ __align__(16) char A2[2][128 * 64];
  __shared__ __align__(16) char Bs[2][128 * 64];
  const int tid = threadIdx.x;
  const int lane = tid & 63, wid = tid >> 6;
  const int quad = lane >> 4, l16 = lane & 15;
  const int m0 = blockIdx.x * 128, n0 = blockIdx.y * 128;
  const int wm = (wid >> 1) * 64, wn = (wid & 1) * 64;
  const int asw = (l16 >> 1) & 3;         // fragment-read swizzle
  i32v4 acc1[4][4] = {};
  i32v4 acc2[4][4] = {};

  auto stage = [&](int bi, int kt) {
    #pragma unroll
    for (int r = 0; r < 2; ++r) {
      int li = r * 256 + tid;
      int row = li >> 2, cs = li & 3;
      int cg = cs ^ ((row >> 1) & 3);
      gload_lds16(xq1 + (size_t)(m0 + row) * EMB + kt * 64 + cg * 16, &A1[bi][li * 16]);
      gload_lds16(xq2 + (size_t)(m0 + row) * EMB + kt * 64 + cg * 16, &A2[bi][li * 16]);
      gload_lds16(w8  + (size_t)(n0 + row) * EMB + kt * 64 + cg * 16, &Bs[bi][li * 16]);
    }
  };

  stage(0, 0);                            // preload tile 0 (cold drain once)
  for (int kt = 0; kt < EMB / 64; ++kt) {
    const int bi = kt & 1;
    __syncthreads();                      // tile kt staged; prev buf's readers done
    if (kt + 1 < EMB / 64) stage(bi ^ 1, kt + 1);   // prefetch, in flight
    i32v4 af1[4], af2[4], bfr[4];
    #pragma unroll
    for (int i = 0; i < 4; ++i) {
      int arow = wm + i * 16 + l16;
      int off = arow * 64 + ((quad ^ asw) * 16);
      af1[i] = *(const i32v4*)&A1[bi][off];
      af2[i] = *(const i32v4*)&A2[bi][off];
      int brow = wn + i * 16 + l16;
      bfr[i] = *(const i32v4*)&Bs[bi][brow * 64 + ((quad ^ asw) * 16)];
    }
    #pragma unroll
    for (int i = 0; i < 4; ++i)
      #pragma unroll
      for (int j = 0; j < 4; ++j) {
        acc1[i][j] = MFMAI8(af1[i], bfr[j], acc1[i][j]);
        acc2[i][j] = MFMAI8(af2[i], bfr[j], acc2[i][j]);
      }
  }
  const float S1 = 0.0625f, S2 = 1.f / 4096.f;
  const float QSCALE = 0.18033688011112042f;   // 0.125 * log2(e)
  #pragma unroll
  for (int i = 0; i < 4; ++i)
    #pragma unroll
    for (int j = 0; j < 4; ++j) {
      const int n = n0 + wn + j * 16 + l16;
      const int region = n >> 10, c1 = n & 1023, h = c1 >> 6, d = c1 & 63;
      const int m_b = m0 + wm + i * 16 + quad * 4;
      float c[4];
      #pragma unroll
      for (int r = 0; r < 4; ++r)
        c[r] = (float)acc1[i][j][r] * S1 + (float)acc2[i][j][r] * S2;
      if (region == 0) {
        #pragma unroll
        for (int r = 0; r < 4; ++r) {
          int m = m_b + r;
          int b = m >> 11, t = m & (SEQ - 1);
          size_t idx = (((size_t)(b * NHEAD + h) * SEQ + t) << 6) + d;
          float cs = c[r] * QSCALE;
          bf16 hi = (bf16)cs;
          qh[idx] = hi; ql[idx] = (bf16)(cs - (float)hi);
        }
      } else if (region == 1) {
        #pragma unroll
        for (int r = 0; r < 4; ++r) {
          int m = m_b + r;
          int b = m >> 11, t = m & (SEQ - 1);
          size_t idx = (((size_t)(b * NHEAD + h) * SEQ + t) << 6) + d;
          bf16 hi = (bf16)c[r];
          kh[idx] = hi; kl[idx] = (bf16)(c[r] - (float)hi);
        }
      } else {
        // V: write transposed [bh][d][t]; 4 consecutive t -> one 8B store
        bf16v4 pk;
        #pragma unroll
        for (int r = 0; r < 4; ++r) pk[r] = (bf16)c[r];
        int b = m_b >> 11, t = m_b & (SEQ - 1);
        *(bf16v4*)&vt[((size_t)(b * NHEAD + h) * HDIM + d) * SEQ + t] = pk;
      }
    }
}

// ---------------- Flash attention (R2-verified, unchanged) ----------------

__launch_bounds__(256, 2)
__global__ void attn_kernel(const bf16* __restrict__ qh, const bf16* __restrict__ ql,
                            const bf16* __restrict__ kh, const bf16* __restrict__ kl,
                            const bf16* __restrict__ vt, bf16* __restrict__ o) {
  __shared__ __align__(16) char smem[66560];
  // buf b at smem + b*24576: Kh [0,8K) | Kl [8K,16K) | Vt [16K,24K)
  bf16* Qh = (bf16*)smem;               // Q phase overlay (dead after frag read)
  bf16* Ql = (bf16*)(smem + 16384);
  bf16* Pw = (bf16*)(smem + 49152);     // 8 slices * 16*68*2 = 17408 B
  const int tid = threadIdx.x;
  const int lane = tid & 63, wid = tid >> 6;     // 4 waves
  const int quad = lane >> 4, l16 = lane & 15;
  const int xs = l16 & 7;
  const int pair = blockIdx.x;          // 0..7
  const int bh = blockIdx.y;
  const size_t base = (size_t)bh * SEQ * HDIM;

  auto stage_kv = [&](char* dst, int k0) {
    #pragma unroll
    for (int r = 0; r < 2; ++r) {
      int li = r * 256 + tid;
      int srow = li >> 3, scg = (li & 7) ^ (srow & 7);
      gload_lds16(kh + base + (size_t)(k0 + srow) * HDIM + scg * 8, (bf16*)dst + (size_t)li * 8);
      gload_lds16(kl + base + (size_t)(k0 + srow) * HDIM + scg * 8, (bf16*)(dst + 8192) + (size_t)li * 8);
      gload_lds16(vt + base + (size_t)srow * SEQ + k0 + scg * 8,    (bf16*)(dst + 16384) + (size_t)li * 8);
    }
  };

  bf16v8 ones_f;
  {
    bf16 v1 = (l16 == 0) ? (bf16)1.0f : (bf16)0.0f;
    #pragma unroll
    for (int j = 0; j < 8; ++j) ones_f[j] = v1;
  }
  const int b = bh >> 4, h = bh & 15;

  for (int phase = 0; phase < 2; ++phase) {
    const int qt = phase ? (7 - pair) : (8 + pair);
    const int q0 = qt * 128;

    __syncthreads();                    // prior phase's LDS readers done
    // stage Q (hi+lo), swizzled
    #pragma unroll
    for (int r = 0; r < 4; ++r) {
      int li = r * 256 + tid;
      int row = li >> 3, cg = (li & 7) ^ (row & 7);
      gload_lds16(qh + base + (size_t)(q0 + row) * HDIM + cg * 8, &Qh[li * 8]);
      gload_lds16(ql + base + (size_t)(q0 + row) * HDIM + cg * 8, &Ql[li * 8]);
    }
    __syncthreads();
    bf16v8 qhf[2][2], qlf[2][2];
    #pragma unroll
    for (int sub = 0; sub < 2; ++sub)
      #pragma unroll
      for (int kk = 0; kk < 2; ++kk) {
        int off = (wid * 32 + sub * 16 + l16) * 64 + (((kk << 2) | quad) ^ xs) * 8;
        qhf[sub][kk] = *(const bf16v8*)&Qh[off];
        qlf[sub][kk] = *(const bf16v8*)&Ql[off];
      }
    __syncthreads();                    // all waves hold Q frags; bufs free

    f32v4 oacc[2][4] = {};
    f32v4 lacc[2] = {};
    float mrow[2][4];
    #pragma unroll
    for (int s = 0; s < 2; ++s)
      #pragma unroll
      for (int r = 0; r < 4; ++r) mrow[s][r] = -1e30f;

    const int qw0 = q0 + wid * 32;
    const int qrow_hi = qw0 + 31;       // wave-uniform causal limit (covers both subs)
    const int ntiles = 2 * qt + 2;

    stage_kv(smem, 0);                  // preload tile 0 -> buf0 (cold drain once)

    for (int ktile = 0; ktile < ntiles; ++ktile) {
      char* cb = smem + (size_t)((ktile & 1) * 24576);
      char* nb = smem + (size_t)(((ktile + 1) & 1) * 24576);
      __syncthreads();                  // tile ktile staged (all waves); prev buf free
      if (ktile + 1 < ntiles) stage_kv(nb, (ktile + 1) * 64);   // prefetch, in flight
      const int k0 = ktile * 64;
      if (k0 > qrow_hi) continue;       // fully-masked tile for this wave

      bf16* Kh_ = (bf16*)cb;
      bf16* Kl_ = (bf16*)(cb + 8192);
      bf16* Vt_ = (bf16*)(cb + 16384);

      // ---- QK^T: K fragments read once, reused by both sub-tiles ----
      f32v4 sacc[2][4] = {};
      #pragma unroll
      for (int kk = 0; kk < 2; ++kk) {
        const int co = (((kk << 2) | quad) ^ xs) * 8;
        bf16v8 khf[4], klf[4];
        #pragma unroll
        for (int nt = 0; nt < 4; ++nt) {
          khf[nt] = *(const bf16v8*)&Kh_[(nt * 16 + l16) * 64 + co];
          klf[nt] = *(const bf16v8*)&Kl_[(nt * 16 + l16) * 64 + co];
        }
        #pragma unroll
        for (int sub = 0; sub < 2; ++sub)
          #pragma unroll
          for (int nt = 0; nt < 4; ++nt) {
            sacc[sub][nt] = MFMA16(qhf[sub][kk], khf[nt], sacc[sub][nt]);
            sacc[sub][nt] = MFMA16(qhf[sub][kk], klf[nt], sacc[sub][nt]);
            sacc[sub][nt] = MFMA16(qlf[sub][kk], khf[nt], sacc[sub][nt]);
          }
      }

      // ---- softmax per sub-tile (scores already in log2 domain) ----
      #pragma unroll
      for (int sub = 0; sub < 2; ++sub) {
        if (k0 > qw0 + sub * 16 + 15) continue;   // sub fully masked (only sub0 can hit)
        const int qrow_base = qw0 + sub * 16 + quad * 4;
        #pragma unroll
        for (int nt = 0; nt < 4; ++nt) {
          int key = k0 + nt * 16 + l16;
          #pragma unroll
          for (int r = 0; r < 4; ++r)
            if (key > qrow_base + r) sacc[sub][nt][r] = -1e30f;
        }
        float alpha[4];
        #pragma unroll
        for (int r = 0; r < 4; ++r) {
          float mx = fmaxf(fmaxf(sacc[sub][0][r], sacc[sub][1][r]),
                           fmaxf(sacc[sub][2][r], sacc[sub][3][r]));
          DPP_FMAX(mx, 0x128);          // row_ror:8
          DPP_FMAX(mx, 0x124);          // row_ror:4
          DPP_FMAX(mx, 0x122);          // row_ror:2
          DPP_FMAX(mx, 0x121);          // row_ror:1
          float mnew = fmaxf(mrow[sub][r], mx);
          alpha[r] = __builtin_amdgcn_exp2f(mrow[sub][r] - mnew);
          mrow[sub][r] = mnew;
        }
        bf16* pwave = Pw + (wid * 2 + sub) * (16 * 68);
        #pragma unroll
        for (int nt = 0; nt < 4; ++nt)
          #pragma unroll
          for (int r = 0; r < 4; ++r)
            pwave[(quad * 4 + r) * 68 + nt * 16 + l16] =
                (bf16)__builtin_amdgcn_exp2f(sacc[sub][nt][r] - mrow[sub][r]);
        #pragma unroll
        for (int r = 0; r < 4; ++r) {
          lacc[sub][r] *= alpha[r];
          #pragma unroll
          for (int dt = 0; dt < 4; ++dt) oacc[sub][dt][r] *= alpha[r];
        }
      }

      // ---- PV + row-sum: V fragments read once, reused by both sub-tiles ----
      #pragma unroll
      for (int kk = 0; kk < 2; ++kk) {
        const int co = (((kk << 2) | quad) ^ xs) * 8;
        bf16v8 vf[4];
        #pragma unroll
        for (int dt = 0; dt < 4; ++dt)
          vf[dt] = *(const bf16v8*)&Vt_[(dt * 16 + l16) * 64 + co];
        #pragma unroll
        for (int sub = 0; sub < 2; ++sub) {
          if (k0 > qw0 + sub * 16 + 15) continue;
          bf16v8 pf = *(const bf16v8*)&Pw[(wid * 2 + sub) * (16 * 68) + l16 * 68 + kk * 32 + quad * 8];
          lacc[sub] = MFMA16(pf, ones_f, lacc[sub]);
          #pragma unroll
          for (int dt = 0; dt < 4; ++dt)
            oacc[sub][dt] = MFMA16(pf, vf[dt], oacc[sub][dt]);
        }
      }
    }

    // row-sum lives in column 0 (lane l16==0 of each quad) -> broadcast
    #pragma unroll
    for (int sub = 0; sub < 2; ++sub) {
      float lrow[4];
      #pragma unroll
      for (int r = 0; r < 4; ++r) lrow[r] = __shfl(lacc[sub][r], lane & 48, 64);
      #pragma unroll
      for (int dt = 0; dt < 4; ++dt)
        #pragma unroll
        for (int r = 0; r < 4; ++r) {
          int q = q0 + wid * 32 + sub * 16 + quad * 4 + r;
          int d = dt * 16 + l16;
          float val = oacc[sub][dt][r] / lrow[r];
          o[((size_t)(b * SEQ + q)) * EMB + h * HDIM + d] = (bf16)val;
        }
    }
  }
}

// ---------------- out projection ----------------
// Same prefetch-before-compute port: double-buffered LDS (64 KB), stage kt+1
// while computing kt.

__launch_bounds__(256, 2)
__global__ void gemm_out_kernel(const bf16* __restrict__ oin, const bf16* __restrict__ wt,
                                float* __restrict__ out) {
  __shared__ __align__(16) bf16 As_[2][128 * 64];
  __shared__ __align__(16) bf16 Bs_[2][128 * 64];
  const int tid = threadIdx.x;
  const int lane = tid & 63, wid = tid >> 6;
  const int quad = lane >> 4, l16 = lane & 15;
  const int m0 = blockIdx.x * 128, n0 = blockIdx.y * 128;
  const int wm = (wid >> 1) * 64, wn = (wid & 1) * 64;
  f32v4 acc[4][4] = {};

  auto stage = [&](int bi, int kt) {
    #pragma unroll
    for (int r = 0; r < 4; ++r) {
      int li = r * 256 + tid;
      int row = li >> 3, col = (li & 7) * 8;
      gload_lds16(oin + (size_t)(m0 + row) * EMB + kt * 64 + col, &As_[bi][li * 8]);
      gload_lds16(wt  + (size_t)(n0 + row) * EMB + kt * 64 + col, &Bs_[bi][li * 8]);
    }
  };

  stage(0, 0);                          // preload tile 0 (cold drain once)
  for (int kt = 0; kt < EMB / 64; ++kt) {
    const int bi = kt & 1;
    __syncthreads();                    // tile kt staged; prev buf's readers done
    if (kt + 1 < EMB / 64) stage(bi ^ 1, kt + 1);   // prefetch, in flight
    #pragma unroll
    for (int kk = 0; kk < 2; ++kk) {
      bf16v8 af[4], bfr[4];
      #pragma unroll
      for (int i = 0; i < 4; ++i) {
        af[i]  = *(const bf16v8*)&As_[bi][(wm + i * 16 + l16) * 64 + kk * 32 + quad * 8];
        bfr[i] = *(const bf16v8*)&Bs_[bi][(wn + i * 16 + l16) * 64 + kk * 32 + quad * 8];
      }
      #pragma unroll
      for (int i = 0; i < 4; ++i)
        #pragma unroll
        for (int j = 0; j < 4; ++j)
          acc[i][j] = MFMA16(af[i], bfr[j], acc[i][j]);
    }
  }
  #pragma unroll
  for (int i = 0; i < 4; ++i)
    #pragma unroll
    for (int j = 0; j < 4; ++j)
      #pragma unroll
      for (int r = 0; r < 4; ++r) {
        int m = m0 + wm + i * 16 + quad * 4 + r;
        int n = n0 + wn + j * 16 + l16;
        out[(size_t)m * EMB + n] = acc[i][j][r];
      }
}

// ---------------- launch ----------------

extern "C" void kernel_launch(void* const* d_in, const int* in_sizes, int n_in,
                              void* d_out, int out_size, void* d_ws, size_t ws_size,
                              hipStream_t stream) {
  const float* x     = (const float*)d_in[0];
  const float* w_qkv = (const float*)d_in[1];
  const float* w_out = (const float*)d_in[2];
  float* out = (float*)d_out;
  char* ws = (char*)d_ws;

  const size_t SZ  = (size_t)MROWS * EMB * sizeof(bf16);   // 16.78 MB
  const size_t SZ8 = (size_t)MROWS * EMB;                  // 8.39 MB (i8 plane)
  size_t off = 0;
  float* sums = (float*)ws;            off = 256;
  char*  wq8  = (char*)(ws + off);     off += (size_t)NQKV * EMB;               // 3.1 MB
  bf16*  wo_t = (bf16*)(ws + off);     off += (size_t)EMB * EMB * sizeof(bf16); // 2.1 MB
  char*  xq1  = (char*)(ws + off);     off += SZ8;
  char*  xq2  = (char*)(ws + off);     off += SZ8;
  bf16*  qh   = (bf16*)(ws + off);     off += SZ;
  bf16*  ql   = (bf16*)(ws + off);     off += SZ;
  bf16*  kh   = (bf16*)(ws + off);     off += SZ;
  bf16*  kl   = (bf16*)(ws + off);     off += SZ;
  bf16*  vt   = (bf16*)(ws + off);     off += SZ;  // written directly by gemm_qkv
  bf16*  ob   = (bf16*)xq1;   // x planes dead after gemm_qkv -> attn output spans xq1+xq2
  (void)in_sizes; (void)n_in; (void)out_size; (void)ws_size;

  zero2_kernel<<<1, 2, 0, stream>>>(sums);
  abs_sum_kernel<<<256, 256, 0, stream>>>(w_qkv, NQKV * EMB, &sums[0]);
  abs_sum_kernel<<<256, 256, 0, stream>>>(w_out, EMB * EMB, &sums[1]);
  ternarize_i8_kernel<<<(NQKV * EMB) / 256, 256, 0, stream>>>(w_qkv, NQKV * EMB, &sums[0], wq8);
  ternarize_bf16_kernel<<<(EMB * EMB) / 256, 256, 0, stream>>>(w_out, EMB * EMB, &sums[1], wo_t);
  quant_x_kernel<<<(MROWS * EMB) / 256, 256, 0, stream>>>(x, xq1, xq2, MROWS * EMB);
  gemm_qkv_kernel<<<dim3(MROWS / 128, NQKV / 128), 256, 0, stream>>>(xq1, xq2, wq8, qh, ql, kh, kl, vt);
  attn_kernel<<<dim3(8, BSZ * NHEAD), 256, 0, stream>>>(qh, ql, kh, kl, vt, ob);
  gemm_out_kernel<<<dim3(MROWS / 128, EMB / 128), 256, 0, stream>>>(ob, wo_t, out);
}

// Round 10
// 336.911 us; speedup vs baseline: 1.0382x; 1.0382x over previous
//
#include <hip/hip_runtime.h>
#include <hip/hip_bf16.h>

#define EMB   1024
#define NHEAD 16
#define HDIM  64
#define BSZ   4
#define SEQ   2048
#define MROWS (BSZ*SEQ)     // 8192
#define NQKV  (3*EMB)       // 3072

typedef __bf16 bf16;
typedef __bf16 bf16v4 __attribute__((ext_vector_type(4)));
typedef __bf16 bf16v8 __attribute__((ext_vector_type(8)));
typedef float  f32v4  __attribute__((ext_vector_type(4)));
typedef float  f32v16 __attribute__((ext_vector_type(16)));
typedef int    i32v4  __attribute__((ext_vector_type(4)));
typedef int    i32v16 __attribute__((ext_vector_type(16)));

#define MFMA16(a,b,c)   __builtin_amdgcn_mfma_f32_16x16x32_bf16((a),(b),(c),0,0,0)
#define MFMA32B(a,b,c)  __builtin_amdgcn_mfma_f32_32x32x16_bf16((a),(b),(c),0,0,0)
#define MFMAI8_32(a,b,c) __builtin_amdgcn_mfma_i32_32x32x32_i8((a),(b),(c),0,0,0)

__device__ __forceinline__ void gload_lds16(const void* g, void* l) {
  __builtin_amdgcn_global_load_lds((const __attribute__((address_space(1))) void*)g,
                                   (__attribute__((address_space(3))) void*)l,
                                   16, 0, 0);
}

// VALU (DPP) max-reduce over the 16-lane row: removes ds_swizzle from the DS pipe.
#define DPP_FMAX(x, ctrl) do {                                                     \
    int _t = __builtin_amdgcn_update_dpp(0, __float_as_int(x), (ctrl), 0xf, 0xf, true); \
    (x) = fmaxf((x), __int_as_float(_t)); } while (0)

// ---------------- scale reduction + ternarize + quantize ----------------

__global__ void abs_sum_kernel(const float* __restrict__ w, int n, float* out) {
  float s = 0.f;
  for (int i = blockIdx.x * blockDim.x + threadIdx.x; i < n; i += gridDim.x * blockDim.x)
    s += fabsf(w[i]);
  #pragma unroll
  for (int off = 32; off; off >>= 1) s += __shfl_down(s, off, 64);
  __shared__ float red[4];
  int lane = threadIdx.x & 63, wid = threadIdx.x >> 6;
  if (lane == 0) red[wid] = s;
  __syncthreads();
  if (threadIdx.x == 0) atomicAdd(out, red[0] + red[1] + red[2] + red[3]);
}

// fused ternarize: w_qkv -> i8 (exact), w_out -> bf16; one launch
__global__ void ternarize_both_kernel(const float* __restrict__ wqkv,
                                      const float* __restrict__ wout,
                                      const float* __restrict__ sums,
                                      char* __restrict__ out8,
                                      bf16* __restrict__ outb) {
  int i = blockIdx.x * blockDim.x + threadIdx.x;
  const int N1 = NQKV * EMB;
  if (i < N1) {
    float scale = fmaxf(sums[0] / (float)N1, 1e-8f);
    float t = rintf(wqkv[i] / scale);          // RNE == jnp.round
    out8[i] = (char)(int)fmaxf(-1.f, fminf(1.f, t));
  } else {
    int j = i - N1;
    float scale = fmaxf(sums[1] / (float)(EMB * EMB), 1e-8f);
    float t = rintf(wout[j] / scale);
    outb[j] = (bf16)fmaxf(-1.f, fminf(1.f, t));
  }
}

// x -> two i8 planes: x ~= p1/16 + p2/4096 (|err| <= 2.4e-4; exact i32 MFMA accum)
__global__ void quant_x_kernel(const float* __restrict__ x, char* __restrict__ p1,
                               char* __restrict__ p2, int n) {
  int i = blockIdx.x * blockDim.x + threadIdx.x;
  if (i >= n) return;
  float v = x[i];
  float q1 = fminf(fmaxf(rintf(v * 16.f), -127.f), 127.f);
  float r = v - q1 * 0.0625f;
  float q2 = fminf(fmaxf(rintf(r * 4096.f), -127.f), 127.f);
  p1[i] = (char)(int)q1;
  p2[i] = (char)(int)q2;
}

// ---------------- fused QKV GEMM, dual-plane i8, 32x32x32 MFMA ----------------
// R8 single-buffer 2-barrier loop (R9's dbuf regressed; reverted).
// 32x32x32_i8: half the MFMA instructions of 16x16x64 at +12% uBench rate;
// same 12 ds_read_b128/kt, same 128 acc VGPRs.
// C/D layout (HW-verified, shape-determined): col=lane&31,
// row=(reg&3)+8*(reg>>2)+4*(lane>>5). A/B: row/col=lane&31, k=(lane>>5)*16+[0..15].
// V-transpose fused into epilogue (R8-verified).

__launch_bounds__(256, 2)
__global__ void gemm_qkv_kernel(const char* __restrict__ xq1, const char* __restrict__ xq2,
                                const char* __restrict__ w8,
                                bf16* __restrict__ qh, bf16* __restrict__ ql,
                                bf16* __restrict__ kh, bf16* __restrict__ kl,
                                bf16* __restrict__ vt) {
  __shared__ __align__(16) char A1[128 * 64];
  __shared__ __align__(16) char A2[128 * 64];
  __shared__ __align__(16) char Bs[128 * 64];
  const int tid = threadIdx.x;
  const int lane = tid & 63, wid = tid >> 6;
  const int c31 = lane & 31, half = lane >> 5;
  const int m0 = blockIdx.x * 128, n0 = blockIdx.y * 128;
  const int wm = (wid >> 1) * 64, wn = (wid & 1) * 64;
  i32v16 acc1[2][2] = {};
  i32v16 acc2[2][2] = {};

  for (int kt = 0; kt < EMB / 64; ++kt) {
    __syncthreads();
    #pragma unroll
    for (int r = 0; r < 2; ++r) {
      int li = r * 256 + tid;
      int row = li >> 2, cs = li & 3;
      int cg = cs ^ ((row >> 1) & 3);          // store swizzle (4 chunks/row)
      gload_lds16(xq1 + (size_t)(m0 + row) * EMB + kt * 64 + cg * 16, &A1[li * 16]);
      gload_lds16(xq2 + (size_t)(m0 + row) * EMB + kt * 64 + cg * 16, &A2[li * 16]);
      gload_lds16(w8  + (size_t)(n0 + row) * EMB + kt * 64 + cg * 16, &Bs[li * 16]);
    }
    __syncthreads();
    i32v4 a1[2][2], a2[2][2], bq[2][2];        // [ks][ti/tj]
    #pragma unroll
    for (int ks = 0; ks < 2; ++ks)
      #pragma unroll
      for (int tt = 0; tt < 2; ++tt) {
        int arow = wm + tt * 32 + c31;
        int aslot = (ks * 2 + half) ^ ((arow >> 1) & 3);
        a1[ks][tt] = *(const i32v4*)&A1[arow * 64 + aslot * 16];
        a2[ks][tt] = *(const i32v4*)&A2[arow * 64 + aslot * 16];
        int brow = wn + tt * 32 + c31;
        int bslot = (ks * 2 + half) ^ ((brow >> 1) & 3);
        bq[ks][tt] = *(const i32v4*)&Bs[brow * 64 + bslot * 16];
      }
    #pragma unroll
    for (int ks = 0; ks < 2; ++ks)
      #pragma unroll
      for (int ti = 0; ti < 2; ++ti)
        #pragma unroll
        for (int tj = 0; tj < 2; ++tj) {
          acc1[ti][tj] = MFMAI8_32(a1[ks][ti], bq[ks][tj], acc1[ti][tj]);
          acc2[ti][tj] = MFMAI8_32(a2[ks][ti], bq[ks][tj], acc2[ti][tj]);
        }
  }
  const float S1 = 0.0625f, S2 = 1.f / 4096.f;
  const float QSCALE = 0.18033688011112042f;   // 0.125 * log2(e)
  #pragma unroll
  for (int ti = 0; ti < 2; ++ti)
    #pragma unroll
    for (int tj = 0; tj < 2; ++tj) {
      const int n = n0 + wn + tj * 32 + c31;
      const int region = n >> 10, c1 = n & 1023, h = c1 >> 6, d = c1 & 63;
      #pragma unroll
      for (int g = 0; g < 4; ++g) {
        const int m_b = m0 + wm + ti * 32 + 8 * g + 4 * half;   // rows m_b..m_b+3
        float c[4];
        #pragma unroll
        for (int rr = 0; rr < 4; ++rr)
          c[rr] = (float)acc1[ti][tj][g * 4 + rr] * S1 + (float)acc2[ti][tj][g * 4 + rr] * S2;
        if (region == 0) {
          #pragma unroll
          for (int rr = 0; rr < 4; ++rr) {
            int m = m_b + rr;
            int b = m >> 11, t = m & (SEQ - 1);
            size_t idx = (((size_t)(b * NHEAD + h) * SEQ + t) << 6) + d;
            float cs = c[rr] * QSCALE;
            bf16 hi = (bf16)cs;
            qh[idx] = hi; ql[idx] = (bf16)(cs - (float)hi);
          }
        } else if (region == 1) {
          #pragma unroll
          for (int rr = 0; rr < 4; ++rr) {
            int m = m_b + rr;
            int b = m >> 11, t = m & (SEQ - 1);
            size_t idx = (((size_t)(b * NHEAD + h) * SEQ + t) << 6) + d;
            bf16 hi = (bf16)c[rr];
            kh[idx] = hi; kl[idx] = (bf16)(c[rr] - (float)hi);
          }
        } else {
          // V: write transposed [bh][d][t]; 4 consecutive t -> one 8B store
          bf16v4 pk;
          #pragma unroll
          for (int rr = 0; rr < 4; ++rr) pk[rr] = (bf16)c[rr];
          int b = m_b >> 11, t = m_b & (SEQ - 1);
          *(bf16v4*)&vt[((size_t)(b * NHEAD + h) * HDIM + d) * SEQ + t] = pk;
        }
      }
    }
}

// ---------------- Flash attention (R2-verified, unchanged) ----------------

__launch_bounds__(256, 2)
__global__ void attn_kernel(const bf16* __restrict__ qh, const bf16* __restrict__ ql,
                            const bf16* __restrict__ kh, const bf16* __restrict__ kl,
                            const bf16* __restrict__ vt, bf16* __restrict__ o) {
  __shared__ __align__(16) char smem[66560];
  // buf b at smem + b*24576: Kh [0,8K) | Kl [8K,16K) | Vt [16K,24K)
  bf16* Qh = (bf16*)smem;               // Q phase overlay (dead after frag read)
  bf16* Ql = (bf16*)(smem + 16384);
  bf16* Pw = (bf16*)(smem + 49152);     // 8 slices * 16*68*2 = 17408 B
  const int tid = threadIdx.x;
  const int lane = tid & 63, wid = tid >> 6;     // 4 waves
  const int quad = lane >> 4, l16 = lane & 15;
  const int xs = l16 & 7;
  const int pair = blockIdx.x;          // 0..7
  const int bh = blockIdx.y;
  const size_t base = (size_t)bh * SEQ * HDIM;

  auto stage_kv = [&](char* dst, int k0) {
    #pragma unroll
    for (int r = 0; r < 2; ++r) {
      int li = r * 256 + tid;
      int srow = li >> 3, scg = (li & 7) ^ (srow & 7);
      gload_lds16(kh + base + (size_t)(k0 + srow) * HDIM + scg * 8, (bf16*)dst + (size_t)li * 8);
      gload_lds16(kl + base + (size_t)(k0 + srow) * HDIM + scg * 8, (bf16*)(dst + 8192) + (size_t)li * 8);
      gload_lds16(vt + base + (size_t)srow * SEQ + k0 + scg * 8,    (bf16*)(dst + 16384) + (size_t)li * 8);
    }
  };

  bf16v8 ones_f;
  {
    bf16 v1 = (l16 == 0) ? (bf16)1.0f : (bf16)0.0f;
    #pragma unroll
    for (int j = 0; j < 8; ++j) ones_f[j] = v1;
  }
  const int b = bh >> 4, h = bh & 15;

  for (int phase = 0; phase < 2; ++phase) {
    const int qt = phase ? (7 - pair) : (8 + pair);
    const int q0 = qt * 128;

    __syncthreads();                    // prior phase's LDS readers done
    // stage Q (hi+lo), swizzled
    #pragma unroll
    for (int r = 0; r < 4; ++r) {
      int li = r * 256 + tid;
      int row = li >> 3, cg = (li & 7) ^ (row & 7);
      gload_lds16(qh + base + (size_t)(q0 + row) * HDIM + cg * 8, &Qh[li * 8]);
      gload_lds16(ql + base + (size_t)(q0 + row) * HDIM + cg * 8, &Ql[li * 8]);
    }
    __syncthreads();
    bf16v8 qhf[2][2], qlf[2][2];
    #pragma unroll
    for (int sub = 0; sub < 2; ++sub)
      #pragma unroll
      for (int kk = 0; kk < 2; ++kk) {
        int off = (wid * 32 + sub * 16 + l16) * 64 + (((kk << 2) | quad) ^ xs) * 8;
        qhf[sub][kk] = *(const bf16v8*)&Qh[off];
        qlf[sub][kk] = *(const bf16v8*)&Ql[off];
      }
    __syncthreads();                    // all waves hold Q frags; bufs free

    f32v4 oacc[2][4] = {};
    f32v4 lacc[2] = {};
    float mrow[2][4];
    #pragma unroll
    for (int s = 0; s < 2; ++s)
      #pragma unroll
      for (int r = 0; r < 4; ++r) mrow[s][r] = -1e30f;

    const int qw0 = q0 + wid * 32;
    const int qrow_hi = qw0 + 31;       // wave-uniform causal limit (covers both subs)
    const int ntiles = 2 * qt + 2;

    stage_kv(smem, 0);                  // preload tile 0 -> buf0 (cold drain once)

    for (int ktile = 0; ktile < ntiles; ++ktile) {
      char* cb = smem + (size_t)((ktile & 1) * 24576);
      char* nb = smem + (size_t)(((ktile + 1) & 1) * 24576);
      __syncthreads();                  // tile ktile staged (all waves); prev buf free
      if (ktile + 1 < ntiles) stage_kv(nb, (ktile + 1) * 64);   // prefetch, in flight
      const int k0 = ktile * 64;
      if (k0 > qrow_hi) continue;       // fully-masked tile for this wave

      bf16* Kh_ = (bf16*)cb;
      bf16* Kl_ = (bf16*)(cb + 8192);
      bf16* Vt_ = (bf16*)(cb + 16384);

      // ---- QK^T: K fragments read once, reused by both sub-tiles ----
      f32v4 sacc[2][4] = {};
      #pragma unroll
      for (int kk = 0; kk < 2; ++kk) {
        const int co = (((kk << 2) | quad) ^ xs) * 8;
        bf16v8 khf[4], klf[4];
        #pragma unroll
        for (int nt = 0; nt < 4; ++nt) {
          khf[nt] = *(const bf16v8*)&Kh_[(nt * 16 + l16) * 64 + co];
          klf[nt] = *(const bf16v8*)&Kl_[(nt * 16 + l16) * 64 + co];
        }
        #pragma unroll
        for (int sub = 0; sub < 2; ++sub)
          #pragma unroll
          for (int nt = 0; nt < 4; ++nt) {
            sacc[sub][nt] = MFMA16(qhf[sub][kk], khf[nt], sacc[sub][nt]);
            sacc[sub][nt] = MFMA16(qhf[sub][kk], klf[nt], sacc[sub][nt]);
            sacc[sub][nt] = MFMA16(qlf[sub][kk], khf[nt], sacc[sub][nt]);
          }
      }

      // ---- softmax per sub-tile (scores already in log2 domain) ----
      #pragma unroll
      for (int sub = 0; sub < 2; ++sub) {
        if (k0 > qw0 + sub * 16 + 15) continue;   // sub fully masked (only sub0 can hit)
        const int qrow_base = qw0 + sub * 16 + quad * 4;
        #pragma unroll
        for (int nt = 0; nt < 4; ++nt) {
          int key = k0 + nt * 16 + l16;
          #pragma unroll
          for (int r = 0; r < 4; ++r)
            if (key > qrow_base + r) sacc[sub][nt][r] = -1e30f;
        }
        float alpha[4];
        #pragma unroll
        for (int r = 0; r < 4; ++r) {
          float mx = fmaxf(fmaxf(sacc[sub][0][r], sacc[sub][1][r]),
                           fmaxf(sacc[sub][2][r], sacc[sub][3][r]));
          DPP_FMAX(mx, 0x128);          // row_ror:8
          DPP_FMAX(mx, 0x124);          // row_ror:4
          DPP_FMAX(mx, 0x122);          // row_ror:2
          DPP_FMAX(mx, 0x121);          // row_ror:1
          float mnew = fmaxf(mrow[sub][r], mx);
          alpha[r] = __builtin_amdgcn_exp2f(mrow[sub][r] - mnew);
          mrow[sub][r] = mnew;
        }
        bf16* pwave = Pw + (wid * 2 + sub) * (16 * 68);
        #pragma unroll
        for (int nt = 0; nt < 4; ++nt)
          #pragma unroll
          for (int r = 0; r < 4; ++r)
            pwave[(quad * 4 + r) * 68 + nt * 16 + l16] =
                (bf16)__builtin_amdgcn_exp2f(sacc[sub][nt][r] - mrow[sub][r]);
        #pragma unroll
        for (int r = 0; r < 4; ++r) {
          lacc[sub][r] *= alpha[r];
          #pragma unroll
          for (int dt = 0; dt < 4; ++dt) oacc[sub][dt][r] *= alpha[r];
        }
      }

      // ---- PV + row-sum: V fragments read once, reused by both sub-tiles ----
      #pragma unroll
      for (int kk = 0; kk < 2; ++kk) {
        const int co = (((kk << 2) | quad) ^ xs) * 8;
        bf16v8 vf[4];
        #pragma unroll
        for (int dt = 0; dt < 4; ++dt)
          vf[dt] = *(const bf16v8*)&Vt_[(dt * 16 + l16) * 64 + co];
        #pragma unroll
        for (int sub = 0; sub < 2; ++sub) {
          if (k0 > qw0 + sub * 16 + 15) continue;
          bf16v8 pf = *(const bf16v8*)&Pw[(wid * 2 + sub) * (16 * 68) + l16 * 68 + kk * 32 + quad * 8];
          lacc[sub] = MFMA16(pf, ones_f, lacc[sub]);
          #pragma unroll
          for (int dt = 0; dt < 4; ++dt)
            oacc[sub][dt] = MFMA16(pf, vf[dt], oacc[sub][dt]);
        }
      }
    }

    // row-sum lives in column 0 (lane l16==0 of each quad) -> broadcast
    #pragma unroll
    for (int sub = 0; sub < 2; ++sub) {
      float lrow[4];
      #pragma unroll
      for (int r = 0; r < 4; ++r) lrow[r] = __shfl(lacc[sub][r], lane & 48, 64);
      #pragma unroll
      for (int dt = 0; dt < 4; ++dt)
        #pragma unroll
        for (int r = 0; r < 4; ++r) {
          int q = q0 + wid * 32 + sub * 16 + quad * 4 + r;
          int d = dt * 16 + l16;
          float val = oacc[sub][dt][r] / lrow[r];
          o[((size_t)(b * SEQ + q)) * EMB + h * HDIM + d] = (bf16)val;
        }
    }
  }
}

// ---------------- out projection, 32x32x16 bf16 MFMA ----------------
// Half the MFMA instructions at +15% uBench rate. Staging now XOR-swizzled
// (chunk ^ (row&7)) — the old linear layout put a quad's 16 lanes on the
// same 4 banks (16-way conflict on every ds_read_b128).

__launch_bounds__(256, 2)
__global__ void gemm_out_kernel(const bf16* __restrict__ oin, const bf16* __restrict__ wt,
                                float* __restrict__ out) {
  __shared__ __align__(16) bf16 As_[128 * 64];
  __shared__ __align__(16) bf16 Bs_[128 * 64];
  const int tid = threadIdx.x;
  const int lane = tid & 63, wid = tid >> 6;
  const int c31 = lane & 31, half = lane >> 5;
  const int m0 = blockIdx.x * 128, n0 = blockIdx.y * 128;
  const int wm = (wid >> 1) * 64, wn = (wid & 1) * 64;
  f32v16 acc[2][2] = {};

  for (int kt = 0; kt < EMB / 64; ++kt) {
    __syncthreads();
    #pragma unroll
    for (int r = 0; r < 4; ++r) {
      int li = r * 256 + tid;
      int row = li >> 3, cs = li & 7;
      int cg = cs ^ (row & 7);                 // store swizzle (8 chunks/row)
      gload_lds16(oin + (size_t)(m0 + row) * EMB + kt * 64 + cg * 8, &As_[li * 8]);
      gload_lds16(wt  + (size_t)(n0 + row) * EMB + kt * 64 + cg * 8, &Bs_[li * 8]);
    }
    __syncthreads();
    bf16v8 af[4][2], bq[4][2];                 // [ks][ti/tj]
    #pragma unroll
    for (int ks = 0; ks < 4; ++ks)
      #pragma unroll
      for (int tt = 0; tt < 2; ++tt) {
        int arow = wm + tt * 32 + c31;
        int aslot = (2 * ks + half) ^ (arow & 7);
        af[ks][tt] = *(const bf16v8*)&As_[arow * 64 + aslot * 8];
        int brow = wn + tt * 32 + c31;
        int bslot = (2 * ks + half) ^ (brow & 7);
        bq[ks][tt] = *(const bf16v8*)&Bs_[brow * 64 + bslot * 8];
      }
    #pragma unroll
    for (int ks = 0; ks < 4; ++ks)
      #pragma unroll
      for (int ti = 0; ti < 2; ++ti)
        #pragma unroll
        for (int tj = 0; tj < 2; ++tj)
          acc[ti][tj] = MFMA32B(af[ks][ti], bq[ks][tj], acc[ti][tj]);
  }
  #pragma unroll
  for (int ti = 0; ti < 2; ++ti)
    #pragma unroll
    for (int tj = 0; tj < 2; ++tj) {
      const int n = n0 + wn + tj * 32 + c31;
      #pragma unroll
      for (int g = 0; g < 4; ++g) {
        const int m_b = m0 + wm + ti * 32 + 8 * g + 4 * half;
        #pragma unroll
        for (int rr = 0; rr < 4; ++rr)
          out[(size_t)(m_b + rr) * EMB + n] = acc[ti][tj][g * 4 + rr];
      }
    }
}

// ---------------- launch ----------------

extern "C" void kernel_launch(void* const* d_in, const int* in_sizes, int n_in,
                              void* d_out, int out_size, void* d_ws, size_t ws_size,
                              hipStream_t stream) {
  const float* x     = (const float*)d_in[0];
  const float* w_qkv = (const float*)d_in[1];
  const float* w_out = (const float*)d_in[2];
  float* out = (float*)d_out;
  char* ws = (char*)d_ws;

  const size_t SZ  = (size_t)MROWS * EMB * sizeof(bf16);   // 16.78 MB
  const size_t SZ8 = (size_t)MROWS * EMB;                  // 8.39 MB (i8 plane)
  size_t off = 0;
  float* sums = (float*)ws;            off = 256;
  char*  wq8  = (char*)(ws + off);     off += (size_t)NQKV * EMB;               // 3.1 MB
  bf16*  wo_t = (bf16*)(ws + off);     off += (size_t)EMB * EMB * sizeof(bf16); // 2.1 MB
  char*  xq1  = (char*)(ws + off);     off += SZ8;
  char*  xq2  = (char*)(ws + off);     off += SZ8;
  bf16*  qh   = (bf16*)(ws + off);     off += SZ;
  bf16*  ql   = (bf16*)(ws + off);     off += SZ;
  bf16*  kh   = (bf16*)(ws + off);     off += SZ;
  bf16*  kl   = (bf16*)(ws + off);     off += SZ;
  bf16*  vt   = (bf16*)(ws + off);     off += SZ;  // written directly by gemm_qkv
  bf16*  ob   = (bf16*)xq1;   // x planes dead after gemm_qkv -> attn output spans xq1+xq2
  (void)in_sizes; (void)n_in; (void)out_size; (void)ws_size;

  hipMemsetAsync(sums, 0, 2 * sizeof(float), stream);
  abs_sum_kernel<<<256, 256, 0, stream>>>(w_qkv, NQKV * EMB, &sums[0]);
  abs_sum_kernel<<<256, 256, 0, stream>>>(w_out, EMB * EMB, &sums[1]);
  ternarize_both_kernel<<<(NQKV * EMB + EMB * EMB) / 256, 256, 0, stream>>>(w_qkv, w_out, sums, wq8, wo_t);
  quant_x_kernel<<<(MROWS * EMB) / 256, 256, 0, stream>>>(x, xq1, xq2, MROWS * EMB);
  gemm_qkv_kernel<<<dim3(MROWS / 128, NQKV / 128), 256, 0, stream>>>(xq1, xq2, wq8, qh, ql, kh, kl, vt);
  attn_kernel<<<dim3(8, BSZ * NHEAD), 256, 0, stream>>>(qh, ql, kh, kl, vt, ob);
  gemm_out_kernel<<<dim3(MROWS / 128, EMB / 128), 256, 0, stream>>>(ob, wo_t, out);
}

// Round 11
// 326.875 us; speedup vs baseline: 1.0701x; 1.0307x over previous
//
#include <hip/hip_runtime.h>
#include <hip/hip_bf16.h>

#define EMB   1024
#define NHEAD 16
#define HDIM  64
#define BSZ   4
#define SEQ   2048
#define MROWS (BSZ*SEQ)     // 8192
#define NQKV  (3*EMB)       // 3072

typedef __bf16 bf16;
typedef __bf16 bf16v4 __attribute__((ext_vector_type(4)));
typedef __bf16 bf16v8 __attribute__((ext_vector_type(8)));
typedef float  f32v4  __attribute__((ext_vector_type(4)));
typedef float  f32v16 __attribute__((ext_vector_type(16)));
typedef int    i32v4  __attribute__((ext_vector_type(4)));
typedef int    i32v16 __attribute__((ext_vector_type(16)));

#define MFMA16(a,b,c)   __builtin_amdgcn_mfma_f32_16x16x32_bf16((a),(b),(c),0,0,0)
#define MFMA32B(a,b,c)  __builtin_amdgcn_mfma_f32_32x32x16_bf16((a),(b),(c),0,0,0)
#define MFMAI8_32(a,b,c) __builtin_amdgcn_mfma_i32_32x32x32_i8((a),(b),(c),0,0,0)

__device__ __forceinline__ void gload_lds16(const void* g, void* l) {
  __builtin_amdgcn_global_load_lds((const __attribute__((address_space(1))) void*)g,
                                   (__attribute__((address_space(3))) void*)l,
                                   16, 0, 0);
}

// VALU (DPP) max-reduce over the 16-lane row: removes ds_swizzle from the DS pipe.
#define DPP_FMAX(x, ctrl) do {                                                     \
    int _t = __builtin_amdgcn_update_dpp(0, __float_as_int(x), (ctrl), 0xf, 0xf, true); \
    (x) = fmaxf((x), __int_as_float(_t)); } while (0)

// ---------------- scale reduction + ternarize + quantize ----------------

__global__ void abs_sum_kernel(const float* __restrict__ w, int n, float* out) {
  float s = 0.f;
  for (int i = blockIdx.x * blockDim.x + threadIdx.x; i < n; i += gridDim.x * blockDim.x)
    s += fabsf(w[i]);
  #pragma unroll
  for (int off = 32; off; off >>= 1) s += __shfl_down(s, off, 64);
  __shared__ float red[4];
  int lane = threadIdx.x & 63, wid = threadIdx.x >> 6;
  if (lane == 0) red[wid] = s;
  __syncthreads();
  if (threadIdx.x == 0) atomicAdd(out, red[0] + red[1] + red[2] + red[3]);
}

// fused ternarize: w_qkv -> i8 (exact), w_out -> bf16; one launch
__global__ void ternarize_both_kernel(const float* __restrict__ wqkv,
                                      const float* __restrict__ wout,
                                      const float* __restrict__ sums,
                                      char* __restrict__ out8,
                                      bf16* __restrict__ outb) {
  int i = blockIdx.x * blockDim.x + threadIdx.x;
  const int N1 = NQKV * EMB;
  if (i < N1) {
    float scale = fmaxf(sums[0] / (float)N1, 1e-8f);
    float t = rintf(wqkv[i] / scale);          // RNE == jnp.round
    out8[i] = (char)(int)fmaxf(-1.f, fminf(1.f, t));
  } else {
    int j = i - N1;
    float scale = fmaxf(sums[1] / (float)(EMB * EMB), 1e-8f);
    float t = rintf(wout[j] / scale);
    outb[j] = (bf16)fmaxf(-1.f, fminf(1.f, t));
  }
}

// x -> two i8 planes: x ~= p1/16 + p2/4096 (|err| <= 2.4e-4; exact i32 MFMA accum)
__global__ void quant_x_kernel(const float* __restrict__ x, char* __restrict__ p1,
                               char* __restrict__ p2, int n) {
  int i = blockIdx.x * blockDim.x + threadIdx.x;
  if (i >= n) return;
  float v = x[i];
  float q1 = fminf(fmaxf(rintf(v * 16.f), -127.f), 127.f);
  float r = v - q1 * 0.0625f;
  float q2 = fminf(fmaxf(rintf(r * 4096.f), -127.f), 127.f);
  p1[i] = (char)(int)q1;
  p2[i] = (char)(int)q2;
}

// ---------------- fused QKV GEMM, dual-plane i8, 32x32x32 MFMA ----------------
// NEW: counted-vmcnt TRIPLE-buffer pipeline (T4). Per kt: issue next tile's 6
// global_load_lds, s_waitcnt vmcnt(6) (oldest 6 = current tile retired,
// next tile's 6 stay IN FLIGHT across the barrier), raw s_barrier, compute.
// Loads never drain to 0 mid-loop — unlike __syncthreads' implicit
// vmcnt(0), which exposed the full staging latency every iteration.
// Safety: 3 buffers make stage(t+1) target a buffer last read at t-2
// (separated by the t-1 barrier; max wave skew across s_barrier = 1 iter).
// vmcnt in-order retirement (m135) + barrier => all waves' tile-t writes
// visible before any wave reads. LDS 3*24KB=72KB, 2 blocks/CU = 144 <= 160.

__launch_bounds__(256, 2)
__global__ void gemm_qkv_kernel(const char* __restrict__ xq1, const char* __restrict__ xq2,
                                const char* __restrict__ w8,
                                bf16* __restrict__ qh, bf16* __restrict__ ql,
                                bf16* __restrict__ kh, bf16* __restrict__ kl,
                                bf16* __restrict__ vt) {
  __shared__ __align__(16) char A1[3][128 * 64];
  __shared__ __align__(16) char A2[3][128 * 64];
  __shared__ __align__(16) char Bs[3][128 * 64];
  const int tid = threadIdx.x;
  const int lane = tid & 63, wid = tid >> 6;
  const int c31 = lane & 31, half = lane >> 5;
  const int m0 = blockIdx.x * 128, n0 = blockIdx.y * 128;
  const int wm = (wid >> 1) * 64, wn = (wid & 1) * 64;
  i32v16 acc1[2][2] = {};
  i32v16 acc2[2][2] = {};

  auto stage = [&](int bi, int kt) {
    #pragma unroll
    for (int r = 0; r < 2; ++r) {
      int li = r * 256 + tid;
      int row = li >> 2, cs = li & 3;
      int cg = cs ^ ((row >> 1) & 3);          // store swizzle (4 chunks/row)
      gload_lds16(xq1 + (size_t)(m0 + row) * EMB + kt * 64 + cg * 16, &A1[bi][li * 16]);
      gload_lds16(xq2 + (size_t)(m0 + row) * EMB + kt * 64 + cg * 16, &A2[bi][li * 16]);
      gload_lds16(w8  + (size_t)(n0 + row) * EMB + kt * 64 + cg * 16, &Bs[bi][li * 16]);
    }
  };

  stage(0, 0);                                 // prologue: tile 0 in flight
  for (int kt = 0; kt < EMB / 64; ++kt) {
    const int bi = kt % 3;
    if (kt + 1 < EMB / 64) {
      stage((kt + 1) % 3, kt + 1);             // 6 more loads -> 12 outstanding
      asm volatile("s_waitcnt vmcnt(6)" ::: "memory");   // tile kt retired; kt+1 in flight
    } else {
      asm volatile("s_waitcnt vmcnt(0)" ::: "memory");   // tail: drain last tile
    }
    __builtin_amdgcn_s_barrier();              // raw barrier: no implicit vmcnt(0)
    i32v4 a1[2][2], a2[2][2], bq[2][2];        // [ks][ti/tj]
    #pragma unroll
    for (int ks = 0; ks < 2; ++ks)
      #pragma unroll
      for (int tt = 0; tt < 2; ++tt) {
        int arow = wm + tt * 32 + c31;
        int aslot = (ks * 2 + half) ^ ((arow >> 1) & 3);
        a1[ks][tt] = *(const i32v4*)&A1[bi][arow * 64 + aslot * 16];
        a2[ks][tt] = *(const i32v4*)&A2[bi][arow * 64 + aslot * 16];
        int brow = wn + tt * 32 + c31;
        int bslot = (ks * 2 + half) ^ ((brow >> 1) & 3);
        bq[ks][tt] = *(const i32v4*)&Bs[bi][brow * 64 + bslot * 16];
      }
    #pragma unroll
    for (int ks = 0; ks < 2; ++ks)
      #pragma unroll
      for (int ti = 0; ti < 2; ++ti)
        #pragma unroll
        for (int tj = 0; tj < 2; ++tj) {
          acc1[ti][tj] = MFMAI8_32(a1[ks][ti], bq[ks][tj], acc1[ti][tj]);
          acc2[ti][tj] = MFMAI8_32(a2[ks][ti], bq[ks][tj], acc2[ti][tj]);
        }
  }
  const float S1 = 0.0625f, S2 = 1.f / 4096.f;
  const float QSCALE = 0.18033688011112042f;   // 0.125 * log2(e)
  #pragma unroll
  for (int ti = 0; ti < 2; ++ti)
    #pragma unroll
    for (int tj = 0; tj < 2; ++tj) {
      const int n = n0 + wn + tj * 32 + c31;
      const int region = n >> 10, c1 = n & 1023, h = c1 >> 6, d = c1 & 63;
      #pragma unroll
      for (int g = 0; g < 4; ++g) {
        const int m_b = m0 + wm + ti * 32 + 8 * g + 4 * half;   // rows m_b..m_b+3
        float c[4];
        #pragma unroll
        for (int rr = 0; rr < 4; ++rr)
          c[rr] = (float)acc1[ti][tj][g * 4 + rr] * S1 + (float)acc2[ti][tj][g * 4 + rr] * S2;
        if (region == 0) {
          #pragma unroll
          for (int rr = 0; rr < 4; ++rr) {
            int m = m_b + rr;
            int b = m >> 11, t = m & (SEQ - 1);
            size_t idx = (((size_t)(b * NHEAD + h) * SEQ + t) << 6) + d;
            float cs = c[rr] * QSCALE;
            bf16 hi = (bf16)cs;
            qh[idx] = hi; ql[idx] = (bf16)(cs - (float)hi);
          }
        } else if (region == 1) {
          #pragma unroll
          for (int rr = 0; rr < 4; ++rr) {
            int m = m_b + rr;
            int b = m >> 11, t = m & (SEQ - 1);
            size_t idx = (((size_t)(b * NHEAD + h) * SEQ + t) << 6) + d;
            bf16 hi = (bf16)c[rr];
            kh[idx] = hi; kl[idx] = (bf16)(c[rr] - (float)hi);
          }
        } else {
          // V: write transposed [bh][d][t]; 4 consecutive t -> one 8B store
          bf16v4 pk;
          #pragma unroll
          for (int rr = 0; rr < 4; ++rr) pk[rr] = (bf16)c[rr];
          int b = m_b >> 11, t = m_b & (SEQ - 1);
          *(bf16v4*)&vt[((size_t)(b * NHEAD + h) * HDIM + d) * SEQ + t] = pk;
        }
      }
    }
}

// ---------------- Flash attention (R2-verified, unchanged) ----------------

__launch_bounds__(256, 2)
__global__ void attn_kernel(const bf16* __restrict__ qh, const bf16* __restrict__ ql,
                            const bf16* __restrict__ kh, const bf16* __restrict__ kl,
                            const bf16* __restrict__ vt, bf16* __restrict__ o) {
  __shared__ __align__(16) char smem[66560];
  // buf b at smem + b*24576: Kh [0,8K) | Kl [8K,16K) | Vt [16K,24K)
  bf16* Qh = (bf16*)smem;               // Q phase overlay (dead after frag read)
  bf16* Ql = (bf16*)(smem + 16384);
  bf16* Pw = (bf16*)(smem + 49152);     // 8 slices * 16*68*2 = 17408 B
  const int tid = threadIdx.x;
  const int lane = tid & 63, wid = tid >> 6;     // 4 waves
  const int quad = lane >> 4, l16 = lane & 15;
  const int xs = l16 & 7;
  const int pair = blockIdx.x;          // 0..7
  const int bh = blockIdx.y;
  const size_t base = (size_t)bh * SEQ * HDIM;

  auto stage_kv = [&](char* dst, int k0) {
    #pragma unroll
    for (int r = 0; r < 2; ++r) {
      int li = r * 256 + tid;
      int srow = li >> 3, scg = (li & 7) ^ (srow & 7);
      gload_lds16(kh + base + (size_t)(k0 + srow) * HDIM + scg * 8, (bf16*)dst + (size_t)li * 8);
      gload_lds16(kl + base + (size_t)(k0 + srow) * HDIM + scg * 8, (bf16*)(dst + 8192) + (size_t)li * 8);
      gload_lds16(vt + base + (size_t)srow * SEQ + k0 + scg * 8,    (bf16*)(dst + 16384) + (size_t)li * 8);
    }
  };

  bf16v8 ones_f;
  {
    bf16 v1 = (l16 == 0) ? (bf16)1.0f : (bf16)0.0f;
    #pragma unroll
    for (int j = 0; j < 8; ++j) ones_f[j] = v1;
  }
  const int b = bh >> 4, h = bh & 15;

  for (int phase = 0; phase < 2; ++phase) {
    const int qt = phase ? (7 - pair) : (8 + pair);
    const int q0 = qt * 128;

    __syncthreads();                    // prior phase's LDS readers done
    // stage Q (hi+lo), swizzled
    #pragma unroll
    for (int r = 0; r < 4; ++r) {
      int li = r * 256 + tid;
      int row = li >> 3, cg = (li & 7) ^ (row & 7);
      gload_lds16(qh + base + (size_t)(q0 + row) * HDIM + cg * 8, &Qh[li * 8]);
      gload_lds16(ql + base + (size_t)(q0 + row) * HDIM + cg * 8, &Ql[li * 8]);
    }
    __syncthreads();
    bf16v8 qhf[2][2], qlf[2][2];
    #pragma unroll
    for (int sub = 0; sub < 2; ++sub)
      #pragma unroll
      for (int kk = 0; kk < 2; ++kk) {
        int off = (wid * 32 + sub * 16 + l16) * 64 + (((kk << 2) | quad) ^ xs) * 8;
        qhf[sub][kk] = *(const bf16v8*)&Qh[off];
        qlf[sub][kk] = *(const bf16v8*)&Ql[off];
      }
    __syncthreads();                    // all waves hold Q frags; bufs free

    f32v4 oacc[2][4] = {};
    f32v4 lacc[2] = {};
    float mrow[2][4];
    #pragma unroll
    for (int s = 0; s < 2; ++s)
      #pragma unroll
      for (int r = 0; r < 4; ++r) mrow[s][r] = -1e30f;

    const int qw0 = q0 + wid * 32;
    const int qrow_hi = qw0 + 31;       // wave-uniform causal limit (covers both subs)
    const int ntiles = 2 * qt + 2;

    stage_kv(smem, 0);                  // preload tile 0 -> buf0 (cold drain once)

    for (int ktile = 0; ktile < ntiles; ++ktile) {
      char* cb = smem + (size_t)((ktile & 1) * 24576);
      char* nb = smem + (size_t)(((ktile + 1) & 1) * 24576);
      __syncthreads();                  // tile ktile staged (all waves); prev buf free
      if (ktile + 1 < ntiles) stage_kv(nb, (ktile + 1) * 64);   // prefetch, in flight
      const int k0 = ktile * 64;
      if (k0 > qrow_hi) continue;       // fully-masked tile for this wave

      bf16* Kh_ = (bf16*)cb;
      bf16* Kl_ = (bf16*)(cb + 8192);
      bf16* Vt_ = (bf16*)(cb + 16384);

      // ---- QK^T: K fragments read once, reused by both sub-tiles ----
      f32v4 sacc[2][4] = {};
      #pragma unroll
      for (int kk = 0; kk < 2; ++kk) {
        const int co = (((kk << 2) | quad) ^ xs) * 8;
        bf16v8 khf[4], klf[4];
        #pragma unroll
        for (int nt = 0; nt < 4; ++nt) {
          khf[nt] = *(const bf16v8*)&Kh_[(nt * 16 + l16) * 64 + co];
          klf[nt] = *(const bf16v8*)&Kl_[(nt * 16 + l16) * 64 + co];
        }
        #pragma unroll
        for (int sub = 0; sub < 2; ++sub)
          #pragma unroll
          for (int nt = 0; nt < 4; ++nt) {
            sacc[sub][nt] = MFMA16(qhf[sub][kk], khf[nt], sacc[sub][nt]);
            sacc[sub][nt] = MFMA16(qhf[sub][kk], klf[nt], sacc[sub][nt]);
            sacc[sub][nt] = MFMA16(qlf[sub][kk], khf[nt], sacc[sub][nt]);
          }
      }

      // ---- softmax per sub-tile (scores already in log2 domain) ----
      #pragma unroll
      for (int sub = 0; sub < 2; ++sub) {
        if (k0 > qw0 + sub * 16 + 15) continue;   // sub fully masked (only sub0 can hit)
        const int qrow_base = qw0 + sub * 16 + quad * 4;
        #pragma unroll
        for (int nt = 0; nt < 4; ++nt) {
          int key = k0 + nt * 16 + l16;
          #pragma unroll
          for (int r = 0; r < 4; ++r)
            if (key > qrow_base + r) sacc[sub][nt][r] = -1e30f;
        }
        float alpha[4];
        #pragma unroll
        for (int r = 0; r < 4; ++r) {
          float mx = fmaxf(fmaxf(sacc[sub][0][r], sacc[sub][1][r]),
                           fmaxf(sacc[sub][2][r], sacc[sub][3][r]));
          DPP_FMAX(mx, 0x128);          // row_ror:8
          DPP_FMAX(mx, 0x124);          // row_ror:4
          DPP_FMAX(mx, 0x122);          // row_ror:2
          DPP_FMAX(mx, 0x121);          // row_ror:1
          float mnew = fmaxf(mrow[sub][r], mx);
          alpha[r] = __builtin_amdgcn_exp2f(mrow[sub][r] - mnew);
          mrow[sub][r] = mnew;
        }
        bf16* pwave = Pw + (wid * 2 + sub) * (16 * 68);
        #pragma unroll
        for (int nt = 0; nt < 4; ++nt)
          #pragma unroll
          for (int r = 0; r < 4; ++r)
            pwave[(quad * 4 + r) * 68 + nt * 16 + l16] =
                (bf16)__builtin_amdgcn_exp2f(sacc[sub][nt][r] - mrow[sub][r]);
        #pragma unroll
        for (int r = 0; r < 4; ++r) {
          lacc[sub][r] *= alpha[r];
          #pragma unroll
          for (int dt = 0; dt < 4; ++dt) oacc[sub][dt][r] *= alpha[r];
        }
      }

      // ---- PV + row-sum: V fragments read once, reused by both sub-tiles ----
      #pragma unroll
      for (int kk = 0; kk < 2; ++kk) {
        const int co = (((kk << 2) | quad) ^ xs) * 8;
        bf16v8 vf[4];
        #pragma unroll
        for (int dt = 0; dt < 4; ++dt)
          vf[dt] = *(const bf16v8*)&Vt_[(dt * 16 + l16) * 64 + co];
        #pragma unroll
        for (int sub = 0; sub < 2; ++sub) {
          if (k0 > qw0 + sub * 16 + 15) continue;
          bf16v8 pf = *(const bf16v8*)&Pw[(wid * 2 + sub) * (16 * 68) + l16 * 68 + kk * 32 + quad * 8];
          lacc[sub] = MFMA16(pf, ones_f, lacc[sub]);
          #pragma unroll
          for (int dt = 0; dt < 4; ++dt)
            oacc[sub][dt] = MFMA16(pf, vf[dt], oacc[sub][dt]);
        }
      }
    }

    // row-sum lives in column 0 (lane l16==0 of each quad) -> broadcast
    #pragma unroll
    for (int sub = 0; sub < 2; ++sub) {
      float lrow[4];
      #pragma unroll
      for (int r = 0; r < 4; ++r) lrow[r] = __shfl(lacc[sub][r], lane & 48, 64);
      #pragma unroll
      for (int dt = 0; dt < 4; ++dt)
        #pragma unroll
        for (int r = 0; r < 4; ++r) {
          int q = q0 + wid * 32 + sub * 16 + quad * 4 + r;
          int d = dt * 16 + l16;
          float val = oacc[sub][dt][r] / lrow[r];
          o[((size_t)(b * SEQ + q)) * EMB + h * HDIM + d] = (bf16)val;
        }
    }
  }
}

// ---------------- out projection, 32x32x16 bf16 MFMA (R10, unchanged) ----------------

__launch_bounds__(256, 2)
__global__ void gemm_out_kernel(const bf16* __restrict__ oin, const bf16* __restrict__ wt,
                                float* __restrict__ out) {
  __shared__ __align__(16) bf16 As_[128 * 64];
  __shared__ __align__(16) bf16 Bs_[128 * 64];
  const int tid = threadIdx.x;
  const int lane = tid & 63, wid = tid >> 6;
  const int c31 = lane & 31, half = lane >> 5;
  const int m0 = blockIdx.x * 128, n0 = blockIdx.y * 128;
  const int wm = (wid >> 1) * 64, wn = (wid & 1) * 64;
  f32v16 acc[2][2] = {};

  for (int kt = 0; kt < EMB / 64; ++kt) {
    __syncthreads();
    #pragma unroll
    for (int r = 0; r < 4; ++r) {
      int li = r * 256 + tid;
      int row = li >> 3, cs = li & 7;
      int cg = cs ^ (row & 7);                 // store swizzle (8 chunks/row)
      gload_lds16(oin + (size_t)(m0 + row) * EMB + kt * 64 + cg * 8, &As_[li * 8]);
      gload_lds16(wt  + (size_t)(n0 + row) * EMB + kt * 64 + cg * 8, &Bs_[li * 8]);
    }
    __syncthreads();
    bf16v8 af[4][2], bq[4][2];                 // [ks][ti/tj]
    #pragma unroll
    for (int ks = 0; ks < 4; ++ks)
      #pragma unroll
      for (int tt = 0; tt < 2; ++tt) {
        int arow = wm + tt * 32 + c31;
        int aslot = (2 * ks + half) ^ (arow & 7);
        af[ks][tt] = *(const bf16v8*)&As_[arow * 64 + aslot * 8];
        int brow = wn + tt * 32 + c31;
        int bslot = (2 * ks + half) ^ (brow & 7);
        bq[ks][tt] = *(const bf16v8*)&Bs_[brow * 64 + bslot * 8];
      }
    #pragma unroll
    for (int ks = 0; ks < 4; ++ks)
      #pragma unroll
      for (int ti = 0; ti < 2; ++ti)
        #pragma unroll
        for (int tj = 0; tj < 2; ++tj)
          acc[ti][tj] = MFMA32B(af[ks][ti], bq[ks][tj], acc[ti][tj]);
  }
  #pragma unroll
  for (int ti = 0; ti < 2; ++ti)
    #pragma unroll
    for (int tj = 0; tj < 2; ++tj) {
      const int n = n0 + wn + tj * 32 + c31;
      #pragma unroll
      for (int g = 0; g < 4; ++g) {
        const int m_b = m0 + wm + ti * 32 + 8 * g + 4 * half;
        #pragma unroll
        for (int rr = 0; rr < 4; ++rr)
          out[(size_t)(m_b + rr) * EMB + n] = acc[ti][tj][g * 4 + rr];
      }
    }
}

// ---------------- launch ----------------

extern "C" void kernel_launch(void* const* d_in, const int* in_sizes, int n_in,
                              void* d_out, int out_size, void* d_ws, size_t ws_size,
                              hipStream_t stream) {
  const float* x     = (const float*)d_in[0];
  const float* w_qkv = (const float*)d_in[1];
  const float* w_out = (const float*)d_in[2];
  float* out = (float*)d_out;
  char* ws = (char*)d_ws;

  const size_t SZ  = (size_t)MROWS * EMB * sizeof(bf16);   // 16.78 MB
  const size_t SZ8 = (size_t)MROWS * EMB;                  // 8.39 MB (i8 plane)
  size_t off = 0;
  float* sums = (float*)ws;            off = 256;
  char*  wq8  = (char*)(ws + off);     off += (size_t)NQKV * EMB;               // 3.1 MB
  bf16*  wo_t = (bf16*)(ws + off);     off += (size_t)EMB * EMB * sizeof(bf16); // 2.1 MB
  char*  xq1  = (char*)(ws + off);     off += SZ8;
  char*  xq2  = (char*)(ws + off);     off += SZ8;
  bf16*  qh   = (bf16*)(ws + off);     off += SZ;
  bf16*  ql   = (bf16*)(ws + off);     off += SZ;
  bf16*  kh   = (bf16*)(ws + off);     off += SZ;
  bf16*  kl   = (bf16*)(ws + off);     off += SZ;
  bf16*  vt   = (bf16*)(ws + off);     off += SZ;  // written directly by gemm_qkv
  bf16*  ob   = (bf16*)xq1;   // x planes dead after gemm_qkv -> attn output spans xq1+xq2
  (void)in_sizes; (void)n_in; (void)out_size; (void)ws_size;

  hipMemsetAsync(sums, 0, 2 * sizeof(float), stream);
  abs_sum_kernel<<<256, 256, 0, stream>>>(w_qkv, NQKV * EMB, &sums[0]);
  abs_sum_kernel<<<256, 256, 0, stream>>>(w_out, EMB * EMB, &sums[1]);
  ternarize_both_kernel<<<(NQKV * EMB + EMB * EMB) / 256, 256, 0, stream>>>(w_qkv, w_out, sums, wq8, wo_t);
  quant_x_kernel<<<(MROWS * EMB) / 256, 256, 0, stream>>>(x, xq1, xq2, MROWS * EMB);
  gemm_qkv_kernel<<<dim3(MROWS / 128, NQKV / 128), 256, 0, stream>>>(xq1, xq2, wq8, qh, ql, kh, kl, vt);
  attn_kernel<<<dim3(8, BSZ * NHEAD), 256, 0, stream>>>(qh, ql, kh, kl, vt, ob);
  gemm_out_kernel<<<dim3(MROWS / 128, EMB / 128), 256, 0, stream>>>(ob, wo_t, out);
}

// Round 12
// 315.452 us; speedup vs baseline: 1.1089x; 1.0362x over previous
//
#include <hip/hip_runtime.h>
#include <hip/hip_bf16.h>

#define EMB   1024
#define NHEAD 16
#define HDIM  64
#define BSZ   4
#define SEQ   2048
#define MROWS (BSZ*SEQ)     // 8192
#define NQKV  (3*EMB)       // 3072

typedef __bf16 bf16;
typedef __bf16 bf16v4 __attribute__((ext_vector_type(4)));
typedef __bf16 bf16v8 __attribute__((ext_vector_type(8)));
typedef float  f32v4  __attribute__((ext_vector_type(4)));
typedef float  f32v16 __attribute__((ext_vector_type(16)));
typedef int    i32v4  __attribute__((ext_vector_type(4)));
typedef int    i32v16 __attribute__((ext_vector_type(16)));
typedef char   c8v4   __attribute__((ext_vector_type(4)));

#define MFMA16(a,b,c)   __builtin_amdgcn_mfma_f32_16x16x32_bf16((a),(b),(c),0,0,0)
#define MFMA32B(a,b,c)  __builtin_amdgcn_mfma_f32_32x32x16_bf16((a),(b),(c),0,0,0)
#define MFMAI8_32(a,b,c) __builtin_amdgcn_mfma_i32_32x32x32_i8((a),(b),(c),0,0,0)

__device__ __forceinline__ void gload_lds16(const void* g, void* l) {
  __builtin_amdgcn_global_load_lds((const __attribute__((address_space(1))) void*)g,
                                   (__attribute__((address_space(3))) void*)l,
                                   16, 0, 0);
}

// VALU (DPP) max-reduce over the 16-lane row: removes ds_swizzle from the DS pipe.
#define DPP_FMAX(x, ctrl) do {                                                     \
    int _t = __builtin_amdgcn_update_dpp(0, __float_as_int(x), (ctrl), 0xf, 0xf, true); \
    (x) = fmaxf((x), __int_as_float(_t)); } while (0)

// ---------------- scale reduction + ternarize + quantize (float4-vectorized) ----------------

__global__ void abs_sum_kernel(const float4* __restrict__ w, int n4, float* out) {
  float s = 0.f;
  for (int i = blockIdx.x * blockDim.x + threadIdx.x; i < n4; i += gridDim.x * blockDim.x) {
    float4 v = w[i];
    s += fabsf(v.x) + fabsf(v.y) + fabsf(v.z) + fabsf(v.w);
  }
  #pragma unroll
  for (int off = 32; off; off >>= 1) s += __shfl_down(s, off, 64);
  __shared__ float red[4];
  int lane = threadIdx.x & 63, wid = threadIdx.x >> 6;
  if (lane == 0) red[wid] = s;
  __syncthreads();
  if (threadIdx.x == 0) atomicAdd(out, red[0] + red[1] + red[2] + red[3]);
}

// fused ternarize: w_qkv -> i8 (exact), w_out -> bf16; one launch; float4 in
__global__ void ternarize_both_kernel(const float4* __restrict__ wqkv,
                                      const float4* __restrict__ wout,
                                      const float* __restrict__ sums,
                                      c8v4* __restrict__ out8,
                                      bf16v4* __restrict__ outb) {
  int i = blockIdx.x * blockDim.x + threadIdx.x;
  const int N1_4 = (NQKV * EMB) / 4;
  if (i < N1_4) {
    float scale = fmaxf(sums[0] / (float)(NQKV * EMB), 1e-8f);
    float4 v = wqkv[i];
    c8v4 o;
    o[0] = (char)(int)fmaxf(-1.f, fminf(1.f, rintf(v.x / scale)));
    o[1] = (char)(int)fmaxf(-1.f, fminf(1.f, rintf(v.y / scale)));
    o[2] = (char)(int)fmaxf(-1.f, fminf(1.f, rintf(v.z / scale)));
    o[3] = (char)(int)fmaxf(-1.f, fminf(1.f, rintf(v.w / scale)));
    out8[i] = o;
  } else {
    int j = i - N1_4;
    float scale = fmaxf(sums[1] / (float)(EMB * EMB), 1e-8f);
    float4 v = wout[j];
    bf16v4 o;
    o[0] = (bf16)fmaxf(-1.f, fminf(1.f, rintf(v.x / scale)));
    o[1] = (bf16)fmaxf(-1.f, fminf(1.f, rintf(v.y / scale)));
    o[2] = (bf16)fmaxf(-1.f, fminf(1.f, rintf(v.z / scale)));
    o[3] = (bf16)fmaxf(-1.f, fminf(1.f, rintf(v.w / scale)));
    outb[j] = o;
  }
}

// x -> two i8 planes: x ~= p1/16 + p2/4096 (|err| <= 2.4e-4; exact i32 MFMA accum)
__global__ void quant_x_kernel(const float4* __restrict__ x, c8v4* __restrict__ p1,
                               c8v4* __restrict__ p2, int n4) {
  int i = blockIdx.x * blockDim.x + threadIdx.x;
  if (i >= n4) return;
  float4 v = x[i];
  c8v4 a, b;
  float vv[4] = {v.x, v.y, v.z, v.w};
  #pragma unroll
  for (int k = 0; k < 4; ++k) {
    float q1 = fminf(fmaxf(rintf(vv[k] * 16.f), -127.f), 127.f);
    float r = vv[k] - q1 * 0.0625f;
    float q2 = fminf(fmaxf(rintf(r * 4096.f), -127.f), 127.f);
    a[k] = (char)(int)q1;
    b[k] = (char)(int)q2;
  }
  p1[i] = a;
  p2[i] = b;
}

// ---------------- fused QKV GEMM, dual-plane i8, 32x32x32 MFMA ----------------
// R11-verified counted-vmcnt TRIPLE-buffer pipeline (unchanged; measured -10us).

__launch_bounds__(256, 2)
__global__ void gemm_qkv_kernel(const char* __restrict__ xq1, const char* __restrict__ xq2,
                                const char* __restrict__ w8,
                                bf16* __restrict__ qh, bf16* __restrict__ ql,
                                bf16* __restrict__ kh, bf16* __restrict__ kl,
                                bf16* __restrict__ vt) {
  __shared__ __align__(16) char A1[3][128 * 64];
  __shared__ __align__(16) char A2[3][128 * 64];
  __shared__ __align__(16) char Bs[3][128 * 64];
  const int tid = threadIdx.x;
  const int lane = tid & 63, wid = tid >> 6;
  const int c31 = lane & 31, half = lane >> 5;
  const int m0 = blockIdx.x * 128, n0 = blockIdx.y * 128;
  const int wm = (wid >> 1) * 64, wn = (wid & 1) * 64;
  i32v16 acc1[2][2] = {};
  i32v16 acc2[2][2] = {};

  auto stage = [&](int bi, int kt) {
    #pragma unroll
    for (int r = 0; r < 2; ++r) {
      int li = r * 256 + tid;
      int row = li >> 2, cs = li & 3;
      int cg = cs ^ ((row >> 1) & 3);          // store swizzle (4 chunks/row)
      gload_lds16(xq1 + (size_t)(m0 + row) * EMB + kt * 64 + cg * 16, &A1[bi][li * 16]);
      gload_lds16(xq2 + (size_t)(m0 + row) * EMB + kt * 64 + cg * 16, &A2[bi][li * 16]);
      gload_lds16(w8  + (size_t)(n0 + row) * EMB + kt * 64 + cg * 16, &Bs[bi][li * 16]);
    }
  };

  stage(0, 0);                                 // prologue: tile 0 in flight
  for (int kt = 0; kt < EMB / 64; ++kt) {
    const int bi = kt % 3;
    if (kt + 1 < EMB / 64) {
      stage((kt + 1) % 3, kt + 1);             // 6 more loads -> 12 outstanding
      asm volatile("s_waitcnt vmcnt(6)" ::: "memory");   // tile kt retired; kt+1 in flight
    } else {
      asm volatile("s_waitcnt vmcnt(0)" ::: "memory");   // tail: drain last tile
    }
    __builtin_amdgcn_s_barrier();              // raw barrier: no implicit vmcnt(0)
    i32v4 a1[2][2], a2[2][2], bq[2][2];        // [ks][ti/tj]
    #pragma unroll
    for (int ks = 0; ks < 2; ++ks)
      #pragma unroll
      for (int tt = 0; tt < 2; ++tt) {
        int arow = wm + tt * 32 + c31;
        int aslot = (ks * 2 + half) ^ ((arow >> 1) & 3);
        a1[ks][tt] = *(const i32v4*)&A1[bi][arow * 64 + aslot * 16];
        a2[ks][tt] = *(const i32v4*)&A2[bi][arow * 64 + aslot * 16];
        int brow = wn + tt * 32 + c31;
        int bslot = (ks * 2 + half) ^ ((brow >> 1) & 3);
        bq[ks][tt] = *(const i32v4*)&Bs[bi][brow * 64 + bslot * 16];
      }
    #pragma unroll
    for (int ks = 0; ks < 2; ++ks)
      #pragma unroll
      for (int ti = 0; ti < 2; ++ti)
        #pragma unroll
        for (int tj = 0; tj < 2; ++tj) {
          acc1[ti][tj] = MFMAI8_32(a1[ks][ti], bq[ks][tj], acc1[ti][tj]);
          acc2[ti][tj] = MFMAI8_32(a2[ks][ti], bq[ks][tj], acc2[ti][tj]);
        }
  }
  const float S1 = 0.0625f, S2 = 1.f / 4096.f;
  const float QSCALE = 0.18033688011112042f;   // 0.125 * log2(e)
  #pragma unroll
  for (int ti = 0; ti < 2; ++ti)
    #pragma unroll
    for (int tj = 0; tj < 2; ++tj) {
      const int n = n0 + wn + tj * 32 + c31;
      const int region = n >> 10, c1 = n & 1023, h = c1 >> 6, d = c1 & 63;
      #pragma unroll
      for (int g = 0; g < 4; ++g) {
        const int m_b = m0 + wm + ti * 32 + 8 * g + 4 * half;   // rows m_b..m_b+3
        float c[4];
        #pragma unroll
        for (int rr = 0; rr < 4; ++rr)
          c[rr] = (float)acc1[ti][tj][g * 4 + rr] * S1 + (float)acc2[ti][tj][g * 4 + rr] * S2;
        if (region == 0) {
          #pragma unroll
          for (int rr = 0; rr < 4; ++rr) {
            int m = m_b + rr;
            int b = m >> 11, t = m & (SEQ - 1);
            size_t idx = (((size_t)(b * NHEAD + h) * SEQ + t) << 6) + d;
            float cs = c[rr] * QSCALE;
            bf16 hi = (bf16)cs;
            qh[idx] = hi; ql[idx] = (bf16)(cs - (float)hi);
          }
        } else if (region == 1) {
          #pragma unroll
          for (int rr = 0; rr < 4; ++rr) {
            int m = m_b + rr;
            int b = m >> 11, t = m & (SEQ - 1);
            size_t idx = (((size_t)(b * NHEAD + h) * SEQ + t) << 6) + d;
            bf16 hi = (bf16)c[rr];
            kh[idx] = hi; kl[idx] = (bf16)(c[rr] - (float)hi);
          }
        } else {
          // V: write transposed [bh][d][t]; 4 consecutive t -> one 8B store
          bf16v4 pk;
          #pragma unroll
          for (int rr = 0; rr < 4; ++rr) pk[rr] = (bf16)c[rr];
          int b = m_b >> 11, t = m_b & (SEQ - 1);
          *(bf16v4*)&vt[((size_t)(b * NHEAD + h) * HDIM + d) * SEQ + t] = pk;
        }
      }
    }
}

// ---------------- Flash attention (R2 structure + T5 setprio) ----------------

__launch_bounds__(256, 2)
__global__ void attn_kernel(const bf16* __restrict__ qh, const bf16* __restrict__ ql,
                            const bf16* __restrict__ kh, const bf16* __restrict__ kl,
                            const bf16* __restrict__ vt, bf16* __restrict__ o) {
  __shared__ __align__(16) char smem[66560];
  // buf b at smem + b*24576: Kh [0,8K) | Kl [8K,16K) | Vt [16K,24K)
  bf16* Qh = (bf16*)smem;               // Q phase overlay (dead after frag read)
  bf16* Ql = (bf16*)(smem + 16384);
  bf16* Pw = (bf16*)(smem + 49152);     // 8 slices * 16*68*2 = 17408 B
  const int tid = threadIdx.x;
  const int lane = tid & 63, wid = tid >> 6;     // 4 waves
  const int quad = lane >> 4, l16 = lane & 15;
  const int xs = l16 & 7;
  const int pair = blockIdx.x;          // 0..7
  const int bh = blockIdx.y;
  const size_t base = (size_t)bh * SEQ * HDIM;

  auto stage_kv = [&](char* dst, int k0) {
    #pragma unroll
    for (int r = 0; r < 2; ++r) {
      int li = r * 256 + tid;
      int srow = li >> 3, scg = (li & 7) ^ (srow & 7);
      gload_lds16(kh + base + (size_t)(k0 + srow) * HDIM + scg * 8, (bf16*)dst + (size_t)li * 8);
      gload_lds16(kl + base + (size_t)(k0 + srow) * HDIM + scg * 8, (bf16*)(dst + 8192) + (size_t)li * 8);
      gload_lds16(vt + base + (size_t)srow * SEQ + k0 + scg * 8,    (bf16*)(dst + 16384) + (size_t)li * 8);
    }
  };

  bf16v8 ones_f;
  {
    bf16 v1 = (l16 == 0) ? (bf16)1.0f : (bf16)0.0f;
    #pragma unroll
    for (int j = 0; j < 8; ++j) ones_f[j] = v1;
  }
  const int b = bh >> 4, h = bh & 15;

  for (int phase = 0; phase < 2; ++phase) {
    const int qt = phase ? (7 - pair) : (8 + pair);
    const int q0 = qt * 128;

    __syncthreads();                    // prior phase's LDS readers done
    // stage Q (hi+lo), swizzled
    #pragma unroll
    for (int r = 0; r < 4; ++r) {
      int li = r * 256 + tid;
      int row = li >> 3, cg = (li & 7) ^ (row & 7);
      gload_lds16(qh + base + (size_t)(q0 + row) * HDIM + cg * 8, &Qh[li * 8]);
      gload_lds16(ql + base + (size_t)(q0 + row) * HDIM + cg * 8, &Ql[li * 8]);
    }
    __syncthreads();
    bf16v8 qhf[2][2], qlf[2][2];
    #pragma unroll
    for (int sub = 0; sub < 2; ++sub)
      #pragma unroll
      for (int kk = 0; kk < 2; ++kk) {
        int off = (wid * 32 + sub * 16 + l16) * 64 + (((kk << 2) | quad) ^ xs) * 8;
        qhf[sub][kk] = *(const bf16v8*)&Qh[off];
        qlf[sub][kk] = *(const bf16v8*)&Ql[off];
      }
    __syncthreads();                    // all waves hold Q frags; bufs free

    f32v4 oacc[2][4] = {};
    f32v4 lacc[2] = {};
    float mrow[2][4];
    #pragma unroll
    for (int s = 0; s < 2; ++s)
      #pragma unroll
      for (int r = 0; r < 4; ++r) mrow[s][r] = -1e30f;

    const int qw0 = q0 + wid * 32;
    const int qrow_hi = qw0 + 31;       // wave-uniform causal limit (covers both subs)
    const int ntiles = 2 * qt + 2;

    stage_kv(smem, 0);                  // preload tile 0 -> buf0 (cold drain once)

    for (int ktile = 0; ktile < ntiles; ++ktile) {
      char* cb = smem + (size_t)((ktile & 1) * 24576);
      char* nb = smem + (size_t)(((ktile + 1) & 1) * 24576);
      __syncthreads();                  // tile ktile staged (all waves); prev buf free
      if (ktile + 1 < ntiles) stage_kv(nb, (ktile + 1) * 64);   // prefetch, in flight
      const int k0 = ktile * 64;
      if (k0 > qrow_hi) continue;       // fully-masked tile for this wave

      bf16* Kh_ = (bf16*)cb;
      bf16* Kl_ = (bf16*)(cb + 8192);
      bf16* Vt_ = (bf16*)(cb + 16384);

      // ---- QK^T: K fragments read once, reused by both sub-tiles ----
      f32v4 sacc[2][4] = {};
      __builtin_amdgcn_s_setprio(1);    // T5: favor this wave while MFMA-dense
      #pragma unroll
      for (int kk = 0; kk < 2; ++kk) {
        const int co = (((kk << 2) | quad) ^ xs) * 8;
        bf16v8 khf[4], klf[4];
        #pragma unroll
        for (int nt = 0; nt < 4; ++nt) {
          khf[nt] = *(const bf16v8*)&Kh_[(nt * 16 + l16) * 64 + co];
          klf[nt] = *(const bf16v8*)&Kl_[(nt * 16 + l16) * 64 + co];
        }
        #pragma unroll
        for (int sub = 0; sub < 2; ++sub)
          #pragma unroll
          for (int nt = 0; nt < 4; ++nt) {
            sacc[sub][nt] = MFMA16(qhf[sub][kk], khf[nt], sacc[sub][nt]);
            sacc[sub][nt] = MFMA16(qhf[sub][kk], klf[nt], sacc[sub][nt]);
            sacc[sub][nt] = MFMA16(qlf[sub][kk], khf[nt], sacc[sub][nt]);
          }
      }
      __builtin_amdgcn_s_setprio(0);

      // ---- softmax per sub-tile (scores already in log2 domain) ----
      #pragma unroll
      for (int sub = 0; sub < 2; ++sub) {
        if (k0 > qw0 + sub * 16 + 15) continue;   // sub fully masked (only sub0 can hit)
        const int qrow_base = qw0 + sub * 16 + quad * 4;
        #pragma unroll
        for (int nt = 0; nt < 4; ++nt) {
          int key = k0 + nt * 16 + l16;
          #pragma unroll
          for (int r = 0; r < 4; ++r)
            if (key > qrow_base + r) sacc[sub][nt][r] = -1e30f;
        }
        float alpha[4];
        #pragma unroll
        for (int r = 0; r < 4; ++r) {
          float mx = fmaxf(fmaxf(sacc[sub][0][r], sacc[sub][1][r]),
                           fmaxf(sacc[sub][2][r], sacc[sub][3][r]));
          DPP_FMAX(mx, 0x128);          // row_ror:8
          DPP_FMAX(mx, 0x124);          // row_ror:4
          DPP_FMAX(mx, 0x122);          // row_ror:2
          DPP_FMAX(mx, 0x121);          // row_ror:1
          float mnew = fmaxf(mrow[sub][r], mx);
          alpha[r] = __builtin_amdgcn_exp2f(mrow[sub][r] - mnew);
          mrow[sub][r] = mnew;
        }
        bf16* pwave = Pw + (wid * 2 + sub) * (16 * 68);
        #pragma unroll
        for (int nt = 0; nt < 4; ++nt)
          #pragma unroll
          for (int r = 0; r < 4; ++r)
            pwave[(quad * 4 + r) * 68 + nt * 16 + l16] =
                (bf16)__builtin_amdgcn_exp2f(sacc[sub][nt][r] - mrow[sub][r]);
        #pragma unroll
        for (int r = 0; r < 4; ++r) {
          lacc[sub][r] *= alpha[r];
          #pragma unroll
          for (int dt = 0; dt < 4; ++dt) oacc[sub][dt][r] *= alpha[r];
        }
      }

      // ---- PV + row-sum: V fragments read once, reused by both sub-tiles ----
      __builtin_amdgcn_s_setprio(1);
      #pragma unroll
      for (int kk = 0; kk < 2; ++kk) {
        const int co = (((kk << 2) | quad) ^ xs) * 8;
        bf16v8 vf[4];
        #pragma unroll
        for (int dt = 0; dt < 4; ++dt)
          vf[dt] = *(const bf16v8*)&Vt_[(dt * 16 + l16) * 64 + co];
        #pragma unroll
        for (int sub = 0; sub < 2; ++sub) {
          if (k0 > qw0 + sub * 16 + 15) continue;
          bf16v8 pf = *(const bf16v8*)&Pw[(wid * 2 + sub) * (16 * 68) + l16 * 68 + kk * 32 + quad * 8];
          lacc[sub] = MFMA16(pf, ones_f, lacc[sub]);
          #pragma unroll
          for (int dt = 0; dt < 4; ++dt)
            oacc[sub][dt] = MFMA16(pf, vf[dt], oacc[sub][dt]);
        }
      }
      __builtin_amdgcn_s_setprio(0);
    }

    // row-sum lives in column 0 (lane l16==0 of each quad) -> broadcast
    #pragma unroll
    for (int sub = 0; sub < 2; ++sub) {
      float lrow[4];
      #pragma unroll
      for (int r = 0; r < 4; ++r) lrow[r] = __shfl(lacc[sub][r], lane & 48, 64);
      #pragma unroll
      for (int dt = 0; dt < 4; ++dt)
        #pragma unroll
        for (int r = 0; r < 4; ++r) {
          int q = q0 + wid * 32 + sub * 16 + quad * 4 + r;
          int d = dt * 16 + l16;
          float val = oacc[sub][dt][r] / lrow[r];
          o[((size_t)(b * SEQ + q)) * EMB + h * HDIM + d] = (bf16)val;
        }
    }
  }
}

// ---------------- out projection, 32x32x16 bf16, counted-vmcnt 4-buf pipeline ----------------
// BK=32, 4 buffers (64 KB LDS, keeps 2 blocks/CU), 2-deep prefetch.
// Per iter: stage tile kt+2, vmcnt(8) (tiles kt+1,kt+2 in flight; kt retired),
// raw barrier, compute. Hazard: stage((t+2)&3) vs laggard readers of (t-1)&3 —
// distinct mod 4. Same protocol as gemm_qkv's R11-verified pipeline.

__launch_bounds__(256, 2)
__global__ void gemm_out_kernel(const bf16* __restrict__ oin, const bf16* __restrict__ wt,
                                float* __restrict__ out) {
  __shared__ __align__(16) bf16 As_[4][128 * 32];
  __shared__ __align__(16) bf16 Bs_[4][128 * 32];
  const int tid = threadIdx.x;
  const int lane = tid & 63, wid = tid >> 6;
  const int c31 = lane & 31, half = lane >> 5;
  const int m0 = blockIdx.x * 128, n0 = blockIdx.y * 128;
  const int wm = (wid >> 1) * 64, wn = (wid & 1) * 64;
  f32v16 acc[2][2] = {};
  const int NT = EMB / 32;                     // 32

  auto stage = [&](int bi, int kt) {
    #pragma unroll
    for (int r = 0; r < 2; ++r) {
      int li = r * 256 + tid;
      int row = li >> 2, cs = li & 3;
      int cg = cs ^ ((row >> 1) & 3);          // store swizzle (4 chunks of 16B per row)
      gload_lds16(oin + (size_t)(m0 + row) * EMB + kt * 32 + cg * 8, &As_[bi][li * 8]);
      gload_lds16(wt  + (size_t)(n0 + row) * EMB + kt * 32 + cg * 8, &Bs_[bi][li * 8]);
    }
  };

  stage(0, 0);
  stage(1, 1);                                 // prologue: tiles 0,1 in flight (8 loads)
  for (int kt = 0; kt < NT; ++kt) {
    const int bi = kt & 3;
    if (kt + 2 < NT) {
      stage((kt + 2) & 3, kt + 2);             // 4 more loads -> 12 outstanding
      asm volatile("s_waitcnt vmcnt(8)" ::: "memory");   // tile kt retired; kt+1,kt+2 in flight
    } else if (kt + 1 < NT) {
      asm volatile("s_waitcnt vmcnt(4)" ::: "memory");   // tile kt retired; kt+1 in flight
    } else {
      asm volatile("s_waitcnt vmcnt(0)" ::: "memory");   // tail drain
    }
    __builtin_amdgcn_s_barrier();
    bf16v8 af[2][2], bq[2][2];                 // [ks][ti/tj]
    #pragma unroll
    for (int ks = 0; ks < 2; ++ks)
      #pragma unroll
      for (int tt = 0; tt < 2; ++tt) {
        int arow = wm + tt * 32 + c31;
        int aslot = (2 * ks + half) ^ ((arow >> 1) & 3);
        af[ks][tt] = *(const bf16v8*)&As_[bi][arow * 32 + aslot * 8];
        int brow = wn + tt * 32 + c31;
        int bslot = (2 * ks + half) ^ ((brow >> 1) & 3);
        bq[ks][tt] = *(const bf16v8*)&Bs_[bi][brow * 32 + bslot * 8];
      }
    #pragma unroll
    for (int ks = 0; ks < 2; ++ks)
      #pragma unroll
      for (int ti = 0; ti < 2; ++ti)
        #pragma unroll
        for (int tj = 0; tj < 2; ++tj)
          acc[ti][tj] = MFMA32B(af[ks][ti], bq[ks][tj], acc[ti][tj]);
  }
  #pragma unroll
  for (int ti = 0; ti < 2; ++ti)
    #pragma unroll
    for (int tj = 0; tj < 2; ++tj) {
      const int n = n0 + wn + tj * 32 + c31;
      #pragma unroll
      for (int g = 0; g < 4; ++g) {
        const int m_b = m0 + wm + ti * 32 + 8 * g + 4 * half;
        #pragma unroll
        for (int rr = 0; rr < 4; ++rr)
          out[(size_t)(m_b + rr) * EMB + n] = acc[ti][tj][g * 4 + rr];
      }
    }
}

// ---------------- launch ----------------

extern "C" void kernel_launch(void* const* d_in, const int* in_sizes, int n_in,
                              void* d_out, int out_size, void* d_ws, size_t ws_size,
                              hipStream_t stream) {
  const float* x     = (const float*)d_in[0];
  const float* w_qkv = (const float*)d_in[1];
  const float* w_out = (const float*)d_in[2];
  float* out = (float*)d_out;
  char* ws = (char*)d_ws;

  const size_t SZ  = (size_t)MROWS * EMB * sizeof(bf16);   // 16.78 MB
  const size_t SZ8 = (size_t)MROWS * EMB;                  // 8.39 MB (i8 plane)
  size_t off = 0;
  float* sums = (float*)ws;            off = 256;
  char*  wq8  = (char*)(ws + off);     off += (size_t)NQKV * EMB;               // 3.1 MB
  bf16*  wo_t = (bf16*)(ws + off);     off += (size_t)EMB * EMB * sizeof(bf16); // 2.1 MB
  char*  xq1  = (char*)(ws + off);     off += SZ8;
  char*  xq2  = (char*)(ws + off);     off += SZ8;
  bf16*  qh   = (bf16*)(ws + off);     off += SZ;
  bf16*  ql   = (bf16*)(ws + off);     off += SZ;
  bf16*  kh   = (bf16*)(ws + off);     off += SZ;
  bf16*  kl   = (bf16*)(ws + off);     off += SZ;
  bf16*  vt   = (bf16*)(ws + off);     off += SZ;  // written directly by gemm_qkv
  bf16*  ob   = (bf16*)xq1;   // x planes dead after gemm_qkv -> attn output spans xq1+xq2
  (void)in_sizes; (void)n_in; (void)out_size; (void)ws_size;

  hipMemsetAsync(sums, 0, 2 * sizeof(float), stream);
  abs_sum_kernel<<<256, 256, 0, stream>>>((const float4*)w_qkv, (NQKV * EMB) / 4, &sums[0]);
  abs_sum_kernel<<<256, 256, 0, stream>>>((const float4*)w_out, (EMB * EMB) / 4, &sums[1]);
  ternarize_both_kernel<<<(NQKV * EMB + EMB * EMB) / 1024, 256, 0, stream>>>(
      (const float4*)w_qkv, (const float4*)w_out, sums, (c8v4*)wq8, (bf16v4*)wo_t);
  quant_x_kernel<<<(MROWS * EMB) / 1024, 256, 0, stream>>>(
      (const float4*)x, (c8v4*)xq1, (c8v4*)xq2, (MROWS * EMB) / 4);
  gemm_qkv_kernel<<<dim3(MROWS / 128, NQKV / 128), 256, 0, stream>>>(xq1, xq2, wq8, qh, ql, kh, kl, vt);
  attn_kernel<<<dim3(8, BSZ * NHEAD), 256, 0, stream>>>(qh, ql, kh, kl, vt, ob);
  gemm_out_kernel<<<dim3(MROWS / 128, EMB / 128), 256, 0, stream>>>(ob, wo_t, out);
}

// Round 13
// 311.157 us; speedup vs baseline: 1.1242x; 1.0138x over previous
//
#include <hip/hip_runtime.h>
#include <hip/hip_bf16.h>

#define EMB   1024
#define NHEAD 16
#define HDIM  64
#define BSZ   4
#define SEQ   2048
#define MROWS (BSZ*SEQ)     // 8192
#define NQKV  (3*EMB)       // 3072

typedef __bf16 bf16;
typedef __bf16 bf16v4 __attribute__((ext_vector_type(4)));
typedef __bf16 bf16v8 __attribute__((ext_vector_type(8)));
typedef float  f32v4  __attribute__((ext_vector_type(4)));
typedef float  f32v16 __attribute__((ext_vector_type(16)));
typedef int    i32v4  __attribute__((ext_vector_type(4)));
typedef int    i32v16 __attribute__((ext_vector_type(16)));
typedef char   c8v4   __attribute__((ext_vector_type(4)));

#define MFMA16(a,b,c)   __builtin_amdgcn_mfma_f32_16x16x32_bf16((a),(b),(c),0,0,0)
#define MFMA32B(a,b,c)  __builtin_amdgcn_mfma_f32_32x32x16_bf16((a),(b),(c),0,0,0)
#define MFMAI8_32(a,b,c) __builtin_amdgcn_mfma_i32_32x32x32_i8((a),(b),(c),0,0,0)

__device__ __forceinline__ void gload_lds16(const void* g, void* l) {
  __builtin_amdgcn_global_load_lds((const __attribute__((address_space(1))) void*)g,
                                   (__attribute__((address_space(3))) void*)l,
                                   16, 0, 0);
}

// VALU (DPP) max-reduce over the 16-lane row: removes ds_swizzle from the DS pipe.
#define DPP_FMAX(x, ctrl) do {                                                     \
    int _t = __builtin_amdgcn_update_dpp(0, __float_as_int(x), (ctrl), 0xf, 0xf, true); \
    (x) = fmaxf((x), __int_as_float(_t)); } while (0)

// ---------------- prep: abs-sums (one launch), quantize+ternarize (one launch) ----------------

__global__ void abs_sum2_kernel(const float4* __restrict__ wq, int nq4,
                                const float4* __restrict__ wo, int no4,
                                float* __restrict__ sums) {
  const bool second = blockIdx.x >= 256;
  const float4* w = second ? wo : wq;
  const int n4 = second ? no4 : nq4;
  float* out = second ? &sums[1] : &sums[0];
  const int bid = second ? blockIdx.x - 256 : blockIdx.x;
  float s = 0.f;
  for (int i = bid * blockDim.x + threadIdx.x; i < n4; i += 256 * blockDim.x) {
    float4 v = w[i];
    s += fabsf(v.x) + fabsf(v.y) + fabsf(v.z) + fabsf(v.w);
  }
  #pragma unroll
  for (int off = 32; off; off >>= 1) s += __shfl_down(s, off, 64);
  __shared__ float red[4];
  int lane = threadIdx.x & 63, wid = threadIdx.x >> 6;
  if (lane == 0) red[wid] = s;
  __syncthreads();
  if (threadIdx.x == 0) atomicAdd(out, red[0] + red[1] + red[2] + red[3]);
}

// merged: x -> dual i8 planes (blocks [0,QB)), w_qkv -> i8 / w_out -> bf16 (rest)
__global__ void prep_kernel(const float4* __restrict__ x, c8v4* __restrict__ p1,
                            c8v4* __restrict__ p2,
                            const float4* __restrict__ wqkv, const float4* __restrict__ wout,
                            const float* __restrict__ sums,
                            c8v4* __restrict__ out8, bf16v4* __restrict__ outb) {
  const int QB = (MROWS * EMB) / 1024;                 // 8192 blocks: quant region
  if (blockIdx.x < QB) {
    int i = blockIdx.x * blockDim.x + threadIdx.x;
    float4 v = x[i];
    c8v4 a, b;
    float vv[4] = {v.x, v.y, v.z, v.w};
    #pragma unroll
    for (int k = 0; k < 4; ++k) {
      float q1 = fminf(fmaxf(rintf(vv[k] * 16.f), -127.f), 127.f);
      float r = vv[k] - q1 * 0.0625f;
      float q2 = fminf(fmaxf(rintf(r * 4096.f), -127.f), 127.f);
      a[k] = (char)(int)q1;
      b[k] = (char)(int)q2;
    }
    p1[i] = a;
    p2[i] = b;
  } else {
    int i = (blockIdx.x - QB) * blockDim.x + threadIdx.x;
    const int N1_4 = (NQKV * EMB) / 4;
    if (i < N1_4) {
      float scale = fmaxf(sums[0] / (float)(NQKV * EMB), 1e-8f);
      float4 v = wqkv[i];
      c8v4 o;
      o[0] = (char)(int)fmaxf(-1.f, fminf(1.f, rintf(v.x / scale)));
      o[1] = (char)(int)fmaxf(-1.f, fminf(1.f, rintf(v.y / scale)));
      o[2] = (char)(int)fmaxf(-1.f, fminf(1.f, rintf(v.z / scale)));
      o[3] = (char)(int)fmaxf(-1.f, fminf(1.f, rintf(v.w / scale)));
      out8[i] = o;
    } else {
      int j = i - N1_4;
      float scale = fmaxf(sums[1] / (float)(EMB * EMB), 1e-8f);
      float4 v = wout[j];
      bf16v4 o;
      o[0] = (bf16)fmaxf(-1.f, fminf(1.f, rintf(v.x / scale)));
      o[1] = (bf16)fmaxf(-1.f, fminf(1.f, rintf(v.y / scale)));
      o[2] = (bf16)fmaxf(-1.f, fminf(1.f, rintf(v.z / scale)));
      o[3] = (bf16)fmaxf(-1.f, fminf(1.f, rintf(v.w / scale)));
      outb[j] = o;
    }
  }
}

// ---------------- fused QKV GEMM, dual-plane i8, 32x32x32 MFMA ----------------
// R11 counted-vmcnt triple-buffer, now 2-DEEP: stage moved AFTER the barrier,
// so stage(t+2) targets buffer (t-1)%3 whose reads completed (all waves)
// before barrier(t). Per iter: vmcnt(6); s_barrier; stage(t+2); compute(t).
// Tile t+2's loads are covered by compute(t)+compute(t+1) (~2 phases).

__launch_bounds__(256, 2)
__global__ void gemm_qkv_kernel(const char* __restrict__ xq1, const char* __restrict__ xq2,
                                const char* __restrict__ w8,
                                bf16* __restrict__ qh, bf16* __restrict__ ql,
                                bf16* __restrict__ kh, bf16* __restrict__ kl,
                                bf16* __restrict__ vt) {
  __shared__ __align__(16) char A1[3][128 * 64];
  __shared__ __align__(16) char A2[3][128 * 64];
  __shared__ __align__(16) char Bs[3][128 * 64];
  const int tid = threadIdx.x;
  const int lane = tid & 63, wid = tid >> 6;
  const int c31 = lane & 31, half = lane >> 5;
  const int m0 = blockIdx.x * 128, n0 = blockIdx.y * 128;
  const int wm = (wid >> 1) * 64, wn = (wid & 1) * 64;
  i32v16 acc1[2][2] = {};
  i32v16 acc2[2][2] = {};

  auto stage = [&](int bi, int kt) {
    #pragma unroll
    for (int r = 0; r < 2; ++r) {
      int li = r * 256 + tid;
      int row = li >> 2, cs = li & 3;
      int cg = cs ^ ((row >> 1) & 3);          // store swizzle (4 chunks/row)
      gload_lds16(xq1 + (size_t)(m0 + row) * EMB + kt * 64 + cg * 16, &A1[bi][li * 16]);
      gload_lds16(xq2 + (size_t)(m0 + row) * EMB + kt * 64 + cg * 16, &A2[bi][li * 16]);
      gload_lds16(w8  + (size_t)(n0 + row) * EMB + kt * 64 + cg * 16, &Bs[bi][li * 16]);
    }
  };

  stage(0, 0);
  stage(1, 1);                                 // prologue: tiles 0,1 in flight (12 loads)
  for (int kt = 0; kt < EMB / 64; ++kt) {
    const int bi = kt % 3;
    if (kt + 1 < EMB / 64) {
      asm volatile("s_waitcnt vmcnt(6)" ::: "memory");   // retire tile kt; kt+1 in flight
    } else {
      asm volatile("s_waitcnt vmcnt(0)" ::: "memory");   // tail drain
    }
    __builtin_amdgcn_s_barrier();              // all waves' tile-kt writes visible
    if (kt + 2 < EMB / 64) stage((kt + 2) % 3, kt + 2);  // targets (kt-1)%3: safe post-barrier
    i32v4 a1[2][2], a2[2][2], bq[2][2];        // [ks][ti/tj]
    #pragma unroll
    for (int ks = 0; ks < 2; ++ks)
      #pragma unroll
      for (int tt = 0; tt < 2; ++tt) {
        int arow = wm + tt * 32 + c31;
        int aslot = (ks * 2 + half) ^ ((arow >> 1) & 3);
        a1[ks][tt] = *(const i32v4*)&A1[bi][arow * 64 + aslot * 16];
        a2[ks][tt] = *(const i32v4*)&A2[bi][arow * 64 + aslot * 16];
        int brow = wn + tt * 32 + c31;
        int bslot = (ks * 2 + half) ^ ((brow >> 1) & 3);
        bq[ks][tt] = *(const i32v4*)&Bs[bi][brow * 64 + bslot * 16];
      }
    #pragma unroll
    for (int ks = 0; ks < 2; ++ks)
      #pragma unroll
      for (int ti = 0; ti < 2; ++ti)
        #pragma unroll
        for (int tj = 0; tj < 2; ++tj) {
          acc1[ti][tj] = MFMAI8_32(a1[ks][ti], bq[ks][tj], acc1[ti][tj]);
          acc2[ti][tj] = MFMAI8_32(a2[ks][ti], bq[ks][tj], acc2[ti][tj]);
        }
  }
  const float S1 = 0.0625f, S2 = 1.f / 4096.f;
  const float QSCALE = 0.18033688011112042f;   // 0.125 * log2(e)
  #pragma unroll
  for (int ti = 0; ti < 2; ++ti)
    #pragma unroll
    for (int tj = 0; tj < 2; ++tj) {
      const int n = n0 + wn + tj * 32 + c31;
      const int region = n >> 10, c1 = n & 1023, h = c1 >> 6, d = c1 & 63;
      #pragma unroll
      for (int g = 0; g < 4; ++g) {
        const int m_b = m0 + wm + ti * 32 + 8 * g + 4 * half;   // rows m_b..m_b+3
        float c[4];
        #pragma unroll
        for (int rr = 0; rr < 4; ++rr)
          c[rr] = (float)acc1[ti][tj][g * 4 + rr] * S1 + (float)acc2[ti][tj][g * 4 + rr] * S2;
        if (region == 0) {
          #pragma unroll
          for (int rr = 0; rr < 4; ++rr) {
            int m = m_b + rr;
            int b = m >> 11, t = m & (SEQ - 1);
            size_t idx = (((size_t)(b * NHEAD + h) * SEQ + t) << 6) + d;
            float cs = c[rr] * QSCALE;
            bf16 hi = (bf16)cs;
            qh[idx] = hi; ql[idx] = (bf16)(cs - (float)hi);
          }
        } else if (region == 1) {
          #pragma unroll
          for (int rr = 0; rr < 4; ++rr) {
            int m = m_b + rr;
            int b = m >> 11, t = m & (SEQ - 1);
            size_t idx = (((size_t)(b * NHEAD + h) * SEQ + t) << 6) + d;
            bf16 hi = (bf16)c[rr];
            kh[idx] = hi; kl[idx] = (bf16)(c[rr] - (float)hi);
          }
        } else {
          // V: write transposed [bh][d][t]; 4 consecutive t -> one 8B store
          bf16v4 pk;
          #pragma unroll
          for (int rr = 0; rr < 4; ++rr) pk[rr] = (bf16)c[rr];
          int b = m_b >> 11, t = m_b & (SEQ - 1);
          *(bf16v4*)&vt[((size_t)(b * NHEAD + h) * HDIM + d) * SEQ + t] = pk;
        }
      }
    }
}

// ---------------- Flash attention (R12-verified: R2 structure + T5 setprio) ----------------

__launch_bounds__(256, 2)
__global__ void attn_kernel(const bf16* __restrict__ qh, const bf16* __restrict__ ql,
                            const bf16* __restrict__ kh, const bf16* __restrict__ kl,
                            const bf16* __restrict__ vt, bf16* __restrict__ o) {
  __shared__ __align__(16) char smem[66560];
  // buf b at smem + b*24576: Kh [0,8K) | Kl [8K,16K) | Vt [16K,24K)
  bf16* Qh = (bf16*)smem;               // Q phase overlay (dead after frag read)
  bf16* Ql = (bf16*)(smem + 16384);
  bf16* Pw = (bf16*)(smem + 49152);     // 8 slices * 16*68*2 = 17408 B
  const int tid = threadIdx.x;
  const int lane = tid & 63, wid = tid >> 6;     // 4 waves
  const int quad = lane >> 4, l16 = lane & 15;
  const int xs = l16 & 7;
  const int pair = blockIdx.x;          // 0..7
  const int bh = blockIdx.y;
  const size_t base = (size_t)bh * SEQ * HDIM;

  auto stage_kv = [&](char* dst, int k0) {
    #pragma unroll
    for (int r = 0; r < 2; ++r) {
      int li = r * 256 + tid;
      int srow = li >> 3, scg = (li & 7) ^ (srow & 7);
      gload_lds16(kh + base + (size_t)(k0 + srow) * HDIM + scg * 8, (bf16*)dst + (size_t)li * 8);
      gload_lds16(kl + base + (size_t)(k0 + srow) * HDIM + scg * 8, (bf16*)(dst + 8192) + (size_t)li * 8);
      gload_lds16(vt + base + (size_t)srow * SEQ + k0 + scg * 8,    (bf16*)(dst + 16384) + (size_t)li * 8);
    }
  };

  bf16v8 ones_f;
  {
    bf16 v1 = (l16 == 0) ? (bf16)1.0f : (bf16)0.0f;
    #pragma unroll
    for (int j = 0; j < 8; ++j) ones_f[j] = v1;
  }
  const int b = bh >> 4, h = bh & 15;

  for (int phase = 0; phase < 2; ++phase) {
    const int qt = phase ? (7 - pair) : (8 + pair);
    const int q0 = qt * 128;

    __syncthreads();                    // prior phase's LDS readers done
    // stage Q (hi+lo), swizzled
    #pragma unroll
    for (int r = 0; r < 4; ++r) {
      int li = r * 256 + tid;
      int row = li >> 3, cg = (li & 7) ^ (row & 7);
      gload_lds16(qh + base + (size_t)(q0 + row) * HDIM + cg * 8, &Qh[li * 8]);
      gload_lds16(ql + base + (size_t)(q0 + row) * HDIM + cg * 8, &Ql[li * 8]);
    }
    __syncthreads();
    bf16v8 qhf[2][2], qlf[2][2];
    #pragma unroll
    for (int sub = 0; sub < 2; ++sub)
      #pragma unroll
      for (int kk = 0; kk < 2; ++kk) {
        int off = (wid * 32 + sub * 16 + l16) * 64 + (((kk << 2) | quad) ^ xs) * 8;
        qhf[sub][kk] = *(const bf16v8*)&Qh[off];
        qlf[sub][kk] = *(const bf16v8*)&Ql[off];
      }
    __syncthreads();                    // all waves hold Q frags; bufs free

    f32v4 oacc[2][4] = {};
    f32v4 lacc[2] = {};
    float mrow[2][4];
    #pragma unroll
    for (int s = 0; s < 2; ++s)
      #pragma unroll
      for (int r = 0; r < 4; ++r) mrow[s][r] = -1e30f;

    const int qw0 = q0 + wid * 32;
    const int qrow_hi = qw0 + 31;       // wave-uniform causal limit (covers both subs)
    const int ntiles = 2 * qt + 2;

    stage_kv(smem, 0);                  // preload tile 0 -> buf0 (cold drain once)

    for (int ktile = 0; ktile < ntiles; ++ktile) {
      char* cb = smem + (size_t)((ktile & 1) * 24576);
      char* nb = smem + (size_t)(((ktile + 1) & 1) * 24576);
      __syncthreads();                  // tile ktile staged (all waves); prev buf free
      if (ktile + 1 < ntiles) stage_kv(nb, (ktile + 1) * 64);   // prefetch, in flight
      const int k0 = ktile * 64;
      if (k0 > qrow_hi) continue;       // fully-masked tile for this wave

      bf16* Kh_ = (bf16*)cb;
      bf16* Kl_ = (bf16*)(cb + 8192);
      bf16* Vt_ = (bf16*)(cb + 16384);

      // ---- QK^T: K fragments read once, reused by both sub-tiles ----
      f32v4 sacc[2][4] = {};
      __builtin_amdgcn_s_setprio(1);    // T5: favor this wave while MFMA-dense
      #pragma unroll
      for (int kk = 0; kk < 2; ++kk) {
        const int co = (((kk << 2) | quad) ^ xs) * 8;
        bf16v8 khf[4], klf[4];
        #pragma unroll
        for (int nt = 0; nt < 4; ++nt) {
          khf[nt] = *(const bf16v8*)&Kh_[(nt * 16 + l16) * 64 + co];
          klf[nt] = *(const bf16v8*)&Kl_[(nt * 16 + l16) * 64 + co];
        }
        #pragma unroll
        for (int sub = 0; sub < 2; ++sub)
          #pragma unroll
          for (int nt = 0; nt < 4; ++nt) {
            sacc[sub][nt] = MFMA16(qhf[sub][kk], khf[nt], sacc[sub][nt]);
            sacc[sub][nt] = MFMA16(qhf[sub][kk], klf[nt], sacc[sub][nt]);
            sacc[sub][nt] = MFMA16(qlf[sub][kk], khf[nt], sacc[sub][nt]);
          }
      }
      __builtin_amdgcn_s_setprio(0);

      // ---- softmax per sub-tile (scores already in log2 domain) ----
      #pragma unroll
      for (int sub = 0; sub < 2; ++sub) {
        if (k0 > qw0 + sub * 16 + 15) continue;   // sub fully masked (only sub0 can hit)
        const int qrow_base = qw0 + sub * 16 + quad * 4;
        #pragma unroll
        for (int nt = 0; nt < 4; ++nt) {
          int key = k0 + nt * 16 + l16;
          #pragma unroll
          for (int r = 0; r < 4; ++r)
            if (key > qrow_base + r) sacc[sub][nt][r] = -1e30f;
        }
        float alpha[4];
        #pragma unroll
        for (int r = 0; r < 4; ++r) {
          float mx = fmaxf(fmaxf(sacc[sub][0][r], sacc[sub][1][r]),
                           fmaxf(sacc[sub][2][r], sacc[sub][3][r]));
          DPP_FMAX(mx, 0x128);          // row_ror:8
          DPP_FMAX(mx, 0x124);          // row_ror:4
          DPP_FMAX(mx, 0x122);          // row_ror:2
          DPP_FMAX(mx, 0x121);          // row_ror:1
          float mnew = fmaxf(mrow[sub][r], mx);
          alpha[r] = __builtin_amdgcn_exp2f(mrow[sub][r] - mnew);
          mrow[sub][r] = mnew;
        }
        bf16* pwave = Pw + (wid * 2 + sub) * (16 * 68);
        #pragma unroll
        for (int nt = 0; nt < 4; ++nt)
          #pragma unroll
          for (int r = 0; r < 4; ++r)
            pwave[(quad * 4 + r) * 68 + nt * 16 + l16] =
                (bf16)__builtin_amdgcn_exp2f(sacc[sub][nt][r] - mrow[sub][r]);
        #pragma unroll
        for (int r = 0; r < 4; ++r) {
          lacc[sub][r] *= alpha[r];
          #pragma unroll
          for (int dt = 0; dt < 4; ++dt) oacc[sub][dt][r] *= alpha[r];
        }
      }

      // ---- PV + row-sum: V fragments read once, reused by both sub-tiles ----
      __builtin_amdgcn_s_setprio(1);
      #pragma unroll
      for (int kk = 0; kk < 2; ++kk) {
        const int co = (((kk << 2) | quad) ^ xs) * 8;
        bf16v8 vf[4];
        #pragma unroll
        for (int dt = 0; dt < 4; ++dt)
          vf[dt] = *(const bf16v8*)&Vt_[(dt * 16 + l16) * 64 + co];
        #pragma unroll
        for (int sub = 0; sub < 2; ++sub) {
          if (k0 > qw0 + sub * 16 + 15) continue;
          bf16v8 pf = *(const bf16v8*)&Pw[(wid * 2 + sub) * (16 * 68) + l16 * 68 + kk * 32 + quad * 8];
          lacc[sub] = MFMA16(pf, ones_f, lacc[sub]);
          #pragma unroll
          for (int dt = 0; dt < 4; ++dt)
            oacc[sub][dt] = MFMA16(pf, vf[dt], oacc[sub][dt]);
        }
      }
      __builtin_amdgcn_s_setprio(0);
    }

    // row-sum lives in column 0 (lane l16==0 of each quad) -> broadcast
    #pragma unroll
    for (int sub = 0; sub < 2; ++sub) {
      float lrow[4];
      #pragma unroll
      for (int r = 0; r < 4; ++r) lrow[r] = __shfl(lacc[sub][r], lane & 48, 64);
      #pragma unroll
      for (int dt = 0; dt < 4; ++dt)
        #pragma unroll
        for (int r = 0; r < 4; ++r) {
          int q = q0 + wid * 32 + sub * 16 + quad * 4 + r;
          int d = dt * 16 + l16;
          float val = oacc[sub][dt][r] / lrow[r];
          o[((size_t)(b * SEQ + q)) * EMB + h * HDIM + d] = (bf16)val;
        }
    }
  }
}

// ---------------- out projection, 32x32x16 bf16, counted-vmcnt 4-buf 3-deep ----------------
// Per iter: vmcnt(8|4|0); s_barrier; stage(kt+3) (targets (kt-1)&3: safe
// post-barrier); compute(kt). Tiles kt+1..kt+3 in flight; 3 compute phases
// of latency cover.

__launch_bounds__(256, 2)
__global__ void gemm_out_kernel(const bf16* __restrict__ oin, const bf16* __restrict__ wt,
                                float* __restrict__ out) {
  __shared__ __align__(16) bf16 As_[4][128 * 32];
  __shared__ __align__(16) bf16 Bs_[4][128 * 32];
  const int tid = threadIdx.x;
  const int lane = tid & 63, wid = tid >> 6;
  const int c31 = lane & 31, half = lane >> 5;
  const int m0 = blockIdx.x * 128, n0 = blockIdx.y * 128;
  const int wm = (wid >> 1) * 64, wn = (wid & 1) * 64;
  f32v16 acc[2][2] = {};
  const int NT = EMB / 32;                     // 32

  auto stage = [&](int bi, int kt) {
    #pragma unroll
    for (int r = 0; r < 2; ++r) {
      int li = r * 256 + tid;
      int row = li >> 2, cs = li & 3;
      int cg = cs ^ ((row >> 1) & 3);          // store swizzle (4 chunks of 16B per row)
      gload_lds16(oin + (size_t)(m0 + row) * EMB + kt * 32 + cg * 8, &As_[bi][li * 8]);
      gload_lds16(wt  + (size_t)(n0 + row) * EMB + kt * 32 + cg * 8, &Bs_[bi][li * 8]);
    }
  };

  stage(0, 0);
  stage(1, 1);
  stage(2, 2);                                 // prologue: tiles 0..2 in flight (12 loads)
  for (int kt = 0; kt < NT; ++kt) {
    const int bi = kt & 3;
    if (kt + 2 < NT) {
      asm volatile("s_waitcnt vmcnt(8)" ::: "memory");   // retire kt; kt+1,kt+2 in flight
    } else if (kt + 1 < NT) {
      asm volatile("s_waitcnt vmcnt(4)" ::: "memory");
    } else {
      asm volatile("s_waitcnt vmcnt(0)" ::: "memory");
    }
    __builtin_amdgcn_s_barrier();
    if (kt + 3 < NT) stage((kt + 3) & 3, kt + 3);        // targets (kt-1)&3: safe post-barrier
    bf16v8 af[2][2], bq[2][2];                 // [ks][ti/tj]
    #pragma unroll
    for (int ks = 0; ks < 2; ++ks)
      #pragma unroll
      for (int tt = 0; tt < 2; ++tt) {
        int arow = wm + tt * 32 + c31;
        int aslot = (2 * ks + half) ^ ((arow >> 1) & 3);
        af[ks][tt] = *(const bf16v8*)&As_[bi][arow * 32 + aslot * 8];
        int brow = wn + tt * 32 + c31;
        int bslot = (2 * ks + half) ^ ((brow >> 1) & 3);
        bq[ks][tt] = *(const bf16v8*)&Bs_[bi][brow * 32 + bslot * 8];
      }
    #pragma unroll
    for (int ks = 0; ks < 2; ++ks)
      #pragma unroll
      for (int ti = 0; ti < 2; ++ti)
        #pragma unroll
        for (int tj = 0; tj < 2; ++tj)
          acc[ti][tj] = MFMA32B(af[ks][ti], bq[ks][tj], acc[ti][tj]);
  }
  #pragma unroll
  for (int ti = 0; ti < 2; ++ti)
    #pragma unroll
    for (int tj = 0; tj < 2; ++tj) {
      const int n = n0 + wn + tj * 32 + c31;
      #pragma unroll
      for (int g = 0; g < 4; ++g) {
        const int m_b = m0 + wm + ti * 32 + 8 * g + 4 * half;
        #pragma unroll
        for (int rr = 0; rr < 4; ++rr)
          out[(size_t)(m_b + rr) * EMB + n] = acc[ti][tj][g * 4 + rr];
      }
    }
}

// ---------------- launch ----------------

extern "C" void kernel_launch(void* const* d_in, const int* in_sizes, int n_in,
                              void* d_out, int out_size, void* d_ws, size_t ws_size,
                              hipStream_t stream) {
  const float* x     = (const float*)d_in[0];
  const float* w_qkv = (const float*)d_in[1];
  const float* w_out = (const float*)d_in[2];
  float* out = (float*)d_out;
  char* ws = (char*)d_ws;

  const size_t SZ  = (size_t)MROWS * EMB * sizeof(bf16);   // 16.78 MB
  const size_t SZ8 = (size_t)MROWS * EMB;                  // 8.39 MB (i8 plane)
  size_t off = 0;
  float* sums = (float*)ws;            off = 256;
  char*  wq8  = (char*)(ws + off);     off += (size_t)NQKV * EMB;               // 3.1 MB
  bf16*  wo_t = (bf16*)(ws + off);     off += (size_t)EMB * EMB * sizeof(bf16); // 2.1 MB
  char*  xq1  = (char*)(ws + off);     off += SZ8;
  char*  xq2  = (char*)(ws + off);     off += SZ8;
  bf16*  qh   = (bf16*)(ws + off);     off += SZ;
  bf16*  ql   = (bf16*)(ws + off);     off += SZ;
  bf16*  kh   = (bf16*)(ws + off);     off += SZ;
  bf16*  kl   = (bf16*)(ws + off);     off += SZ;
  bf16*  vt   = (bf16*)(ws + off);     off += SZ;  // written directly by gemm_qkv
  bf16*  ob   = (bf16*)xq1;   // x planes dead after gemm_qkv -> attn output spans xq1+xq2
  (void)in_sizes; (void)n_in; (void)out_size; (void)ws_size;

  hipMemsetAsync(sums, 0, 2 * sizeof(float), stream);
  abs_sum2_kernel<<<512, 256, 0, stream>>>((const float4*)w_qkv, (NQKV * EMB) / 4,
                                           (const float4*)w_out, (EMB * EMB) / 4, sums);
  prep_kernel<<<(MROWS * EMB) / 1024 + (NQKV * EMB + EMB * EMB) / 1024, 256, 0, stream>>>(
      (const float4*)x, (c8v4*)xq1, (c8v4*)xq2,
      (const float4*)w_qkv, (const float4*)w_out, sums, (c8v4*)wq8, (bf16v4*)wo_t);
  gemm_qkv_kernel<<<dim3(MROWS / 128, NQKV / 128), 256, 0, stream>>>(xq1, xq2, wq8, qh, ql, kh, kl, vt);
  attn_kernel<<<dim3(8, BSZ * NHEAD), 256, 0, stream>>>(qh, ql, kh, kl, vt, ob);
  gemm_out_kernel<<<dim3(MROWS / 128, EMB / 128), 256, 0, stream>>>(ob, wo_t, out);
}